// Round 3
// baseline (238.683 us; speedup 1.0000x reference)
//
#include <hip/hip_runtime.h>
#include <stdint.h>

#define BB 8
#define SS 1374
#define DD 384
#define HH 6
#define HDIM 64
#define MROWS (BB*SS)   // 10992
#define NPFX 5
#define SPAD 1376       // padded S for vt rows (16B-aligned rows)

typedef __attribute__((ext_vector_type(8))) short bf16x8;
typedef __attribute__((ext_vector_type(4))) float f32x4;
typedef __attribute__((ext_vector_type(2))) unsigned int u32x2;
typedef __attribute__((ext_vector_type(4))) unsigned int u32x4;

__device__ __forceinline__ unsigned short f2bf(float f){
  union { float f; unsigned int u; } v; v.f = f;
  return (unsigned short)((v.u + 0x7FFFu + ((v.u >> 16) & 1u)) >> 16);
}
__device__ __forceinline__ float bf2f(unsigned short b){
  union { float f; unsigned int u; } v; v.u = ((unsigned int)b) << 16; return v.f;
}
__device__ __forceinline__ unsigned int pk_bf16(float a, float b){
#if __has_builtin(__builtin_amdgcn_cvt_pk_bf16_f32)
  typedef __attribute__((ext_vector_type(2))) __bf16 bfv2;
  bfv2 p = __builtin_amdgcn_cvt_pk_bf16_f32(a, b);
  union { bfv2 v; unsigned int u; } c; c.v = p; return c.u;
#else
  return (unsigned int)f2bf(a) | ((unsigned int)f2bf(b) << 16);
#endif
}
// async global->LDS, 16B per lane; lds base must be wave-uniform (lane i -> base + i*16B)
__device__ __forceinline__ void gld_lds16(const unsigned short* g, unsigned short* l){
  __builtin_amdgcn_global_load_lds((const __attribute__((address_space(1))) unsigned int*)(g),
                                   (__attribute__((address_space(3))) unsigned int*)(l), 16, 0, 0);
}

// ---------------- prep kernels ----------------
// vectorized f32 -> bf16 cast (4 elements/thread)
__global__ void k_conv_x(const float* __restrict__ x, unsigned short* __restrict__ xb, int n4){
  int i = blockIdx.x*blockDim.x + threadIdx.x;
  if (i >= n4) return;
  f32x4 v = *(const f32x4*)(x + (size_t)i*4);
  u32x2 o; o[0] = pk_bf16(v[0], v[1]); o[1] = pk_bf16(v[2], v[3]);
  *(u32x2*)(xb + (size_t)i*4) = o;
}

// wbT[n][d] (n<1152): transposed concat wq|wk|wv; then woT[n][k] = wo[k*384+n]
__global__ void k_conv_w(const float* __restrict__ wq, const float* __restrict__ wk,
                         const float* __restrict__ wv, const float* __restrict__ wo,
                         unsigned short* __restrict__ wbT, unsigned short* __restrict__ woT){
  int i = blockIdx.x*blockDim.x + threadIdx.x;
  if (i < 1152*384){
    int n = i / 384, d = i % 384;
    const float* w = (n < 384) ? wq : (n < 768) ? wk : wv;
    wbT[i] = f2bf(w[(size_t)d*384 + (n % 384)]);
  } else if (i < 1152*384 + 384*384){
    int j = i - 1152*384;
    int n = j / 384, k = j % 384;
    woT[j] = f2bf(wo[(size_t)k*384 + n]);
  }
}

// xbar[b][d] = sum_s w_s * x[b][s][d]
__global__ void k_xbar(const float* __restrict__ x, float* __restrict__ xbar){
  int b = blockIdx.x / 11, ch = blockIdx.x % 11;
  int d = threadIdx.x;
  int s0 = ch*128, s1 = s0 + 128; if (s1 > SS) s1 = SS;
  float acc = 0.f;
  for (int s = s0; s < s1; ++s){
    float w = (s == 0) ? (1.f/3.f) : (s < 5) ? (1.f/12.f) : (1.f/4107.f);
    acc += w * x[((size_t)b*SS + s)*DD + d];
  }
  atomicAdd(&xbar[b*DD + d], acc);
}

// qbar[b][he] = sum_d xbar[b][d]*wq[d][he] + bq[he]
__global__ void k_qbar(const float* __restrict__ xbar, const float* __restrict__ wq,
                       const float* __restrict__ bq, float* __restrict__ qbar){
  __shared__ float xs[DD];
  int b = blockIdx.x, t = threadIdx.x;
  xs[t] = xbar[b*DD + t];
  __syncthreads();
  float acc = bq[t];
  for (int d = 0; d < DD; ++d) acc += xs[d]*wq[(size_t)d*384 + t];
  qbar[b*384 + t] = acc;
}

// attn_agg[b][s] = (1/48) * sum_he qbar[b][he] * K[b][h][s][e]
__global__ void k_agg(const float* __restrict__ qbar, const unsigned short* __restrict__ kg,
                      float* __restrict__ out_agg){
  __shared__ float qs[384];
  int b = blockIdx.x / 6, sb = blockIdx.x % 6;
  int t = threadIdx.x;
  for (int i = t; i < 384; i += 256) qs[i] = qbar[b*384 + i];
  __syncthreads();
  int s = sb*256 + t;
  if (s >= SS) return;
  float acc = 0.f;
  for (int h = 0; h < HH; ++h){
    const unsigned short* kr = kg + (((size_t)(b*HH + h))*SS + s)*64;
    const float* qh = qs + h*64;
    for (int c = 0; c < 8; ++c){
      u32x4 v = *(const u32x4*)(kr + c*8);
      #pragma unroll
      for (int j = 0; j < 4; ++j){
        unsigned int u = v[j];
        acc += qh[c*8 + 2*j]     * bf2f((unsigned short)(u & 0xFFFFu));
        acc += qh[c*8 + 2*j + 1] * bf2f((unsigned short)(u >> 16));
      }
    }
  }
  out_agg[b*SS + s] = acc * (1.f/48.f);
}

// ---------------- m97-style MFMA GEMM: 128x128 tile, BK=32, global_load_lds staging ----------------
// MODE 0: C(10992x1152) = xb * wbT^T -> qg(*1/8)/kg (B,H,S,64) and vt (B,H,64,SPAD), +bias, bf16
// MODE 1: C(10992x384)  = zo * woT^T -> out fp32 + bo
template<int MODE>
__global__ __launch_bounds__(256) void k_gemm(
    const unsigned short* __restrict__ A, const unsigned short* __restrict__ Bt,
    const float* __restrict__ b0, const float* __restrict__ b1, const float* __restrict__ b2,
    unsigned short* __restrict__ qg, unsigned short* __restrict__ kgp,
    unsigned short* __restrict__ vt, float* __restrict__ out)
{
  int mt = blockIdx.x % 86, nt = blockIdx.x / 86;
  const int t = threadIdx.x;
  const int w = t >> 6, lane = t & 63, quad = lane >> 4, l16 = lane & 15;
  const int wm = w >> 1, wn = w & 1;
  __shared__ unsigned short As[128*32];   // packed (no pad: required by global_load_lds)
  __shared__ unsigned short Bs[128*32];
  f32x4 acc[4][4];
  #pragma unroll
  for (int i=0;i<4;i++)
    #pragma unroll
    for (int j=0;j<4;j++) acc[i][j] = (f32x4){0.f,0.f,0.f,0.f};
  const int m0 = mt*128, n0 = nt*128;
  const int lrow = lane >> 2, lc = lane & 3;   // staging: 16 rows x 4x16B chunks per wave-issue
  // per-lane global row for A (clamped at edge tile; duplicate rows are harmless)
  int ga0 = m0 + w*32 + lrow;       if (ga0 > MROWS-1) ga0 = MROWS-1;
  int ga1 = m0 + w*32 + 16 + lrow;  if (ga1 > MROWS-1) ga1 = MROWS-1;
  const int gb0 = n0 + w*32 + lrow, gb1 = n0 + w*32 + 16 + lrow;
  const unsigned short* a0 = A  + (size_t)ga0*384 + lc*8;
  const unsigned short* a1 = A  + (size_t)ga1*384 + lc*8;
  const unsigned short* bp0 = Bt + (size_t)gb0*384 + lc*8;
  const unsigned short* bp1 = Bt + (size_t)gb1*384 + lc*8;
  unsigned short* As0 = As + (w*32)*32;      // wave-uniform LDS bases
  unsigned short* As1 = As + (w*32 + 16)*32;
  unsigned short* Bs0 = Bs + (w*32)*32;
  unsigned short* Bs1 = Bs + (w*32 + 16)*32;

  for (int kc = 0; kc < 12; ++kc){
    int k0 = kc*32;
    __syncthreads();
    gld_lds16(a0 + k0, As0);
    gld_lds16(a1 + k0, As1);
    gld_lds16(bp0 + k0, Bs0);
    gld_lds16(bp1 + k0, Bs1);
    __syncthreads();
    bf16x8 af[4], bfr[4];
    #pragma unroll
    for (int rf = 0; rf < 4; ++rf)
      af[rf] = *(const bf16x8*)(As + (wm*64 + rf*16 + l16)*32 + quad*8);
    #pragma unroll
    for (int cf = 0; cf < 4; ++cf)
      bfr[cf] = *(const bf16x8*)(Bs + (wn*64 + cf*16 + l16)*32 + quad*8);
    #pragma unroll
    for (int rf = 0; rf < 4; ++rf)
      #pragma unroll
      for (int cf = 0; cf < 4; ++cf)
        acc[rf][cf] = __builtin_amdgcn_mfma_f32_16x16x32_bf16(af[rf], bfr[cf], acc[rf][cf], 0,0,0);
  }
  // epilogue
  #pragma unroll
  for (int cf = 0; cf < 4; ++cf){
    int n = n0 + wn*64 + cf*16 + l16;
    int mat = n / 384, he = n % 384, h = he >> 6, e = he & 63;
    float bias = (MODE==0) ? ((mat==0 ? b0 : (mat==1 ? b1 : b2))[he]) : b0[n];
    float vsc = (MODE==0 && mat==0) ? 0.125f : 1.f;   // fold 1/sqrt(64) into q
    #pragma unroll
    for (int rf = 0; rf < 4; ++rf){
      int rbase = m0 + wm*64 + rf*16 + quad*4;
      if (MODE == 1){
        #pragma unroll
        for (int r4 = 0; r4 < 4; ++r4){
          int rr = rbase + r4;
          if (rr < MROWS) out[(size_t)rr*384 + n] = acc[rf][cf][r4] + bias;
        }
      } else if (mat < 2){
        unsigned short* dst = (mat==0) ? qg : kgp;
        #pragma unroll
        for (int r4 = 0; r4 < 4; ++r4){
          int rr = rbase + r4;
          if (rr < MROWS){
            int b = rr / SS, s = rr % SS;
            dst[(((size_t)(b*HH + h))*SS + s)*64 + e] = f2bf((acc[rf][cf][r4] + bias)*vsc);
          }
        }
      } else {
        // vt[(bh*64+e)*SPAD + s]; row pairs are consecutive s within one batch
        #pragma unroll
        for (int p = 0; p < 2; ++p){
          int rr = rbase + p*2;
          if (rr < MROWS){
            int b = rr / SS, s = rr % SS;
            *(unsigned int*)(vt + ((size_t)(b*HH + h)*64 + e)*SPAD + s) =
                pk_bf16(acc[rf][cf][p*2] + bias, acc[rf][cf][p*2+1] + bias);
          }
        }
      }
    }
  }
}

// ---------------- flash attention (no online max: |z| << 80 so exp is safe) ----------------
#define KSTR 72
__global__ __launch_bounds__(256) void k_attn(
    const unsigned short* __restrict__ qg, const unsigned short* __restrict__ kg,
    const unsigned short* __restrict__ vt, unsigned short* __restrict__ zo,
    const int* __restrict__ kpat)
{
  const int QB = (SS + 63)/64; // 22
  int qb = blockIdx.x % QB, bh = blockIdx.x / QB;
  int t = threadIdx.x, w = t >> 6, lane = t & 63, quad = lane >> 4, l16 = lane & 15;
  int SK = NPFX + kpat[0]; if (SK > SS) SK = SS; if (SK < 1) SK = 1;
  int niter = (SK + 63) >> 6;
  __shared__ unsigned short Ks[64*KSTR];      // [key][e]
  __shared__ unsigned short Vs[64*KSTR];      // [e][key]
  __shared__ unsigned short Ps[4*16*KSTR];    // [wave][q][key] — wave-private
  int q0 = qb*64 + w*16;
  bf16x8 aq[2];
  {
    int qrow = q0 + l16;
    if (qrow < SS){
      const unsigned short* p = qg + ((size_t)bh*SS + qrow)*64;
      aq[0] = *(const bf16x8*)(p + quad*8);
      aq[1] = *(const bf16x8*)(p + 32 + quad*8);
    } else {
      bf16x8 z8 = {0,0,0,0,0,0,0,0};
      aq[0] = z8; aq[1] = z8;
    }
  }
  f32x4 o[4];
  #pragma unroll
  for (int i=0;i<4;i++) o[i] = (f32x4){0.f,0.f,0.f,0.f};
  float rsum[4] = {0.f,0.f,0.f,0.f};

  const int srow = t >> 2, sc = t & 3;
  const unsigned short* kbase = kg + ((size_t)bh*SS)*64;
  const unsigned short* vbase = vt + ((size_t)bh*64)*SPAD;
  u32x4 rk0, rk1, rv0, rv1;
  rk0 = *(const u32x4*)(kbase + (size_t)srow*64 + sc*8);
  rk1 = *(const u32x4*)(kbase + (size_t)srow*64 + (sc+4)*8);
  rv0 = *(const u32x4*)(vbase + (size_t)srow*SPAD + sc*8);
  rv1 = *(const u32x4*)(vbase + (size_t)srow*SPAD + (sc+4)*8);

  for (int it = 0; it < niter; ++it){
    int k0 = it*64;
    __syncthreads();
    *(u32x4*)(Ks + srow*KSTR + sc*8)     = rk0;
    *(u32x4*)(Ks + srow*KSTR + (sc+4)*8) = rk1;
    *(u32x4*)(Vs + srow*KSTR + sc*8)     = rv0;
    *(u32x4*)(Vs + srow*KSTR + (sc+4)*8) = rv1;
    __syncthreads();
    if (it + 1 < niter){
      int kn = k0 + 64;
      rk0 = *(const u32x4*)(kbase + (size_t)(kn + srow)*64 + sc*8);
      rk1 = *(const u32x4*)(kbase + (size_t)(kn + srow)*64 + (sc+4)*8);
      rv0 = *(const u32x4*)(vbase + (size_t)srow*SPAD + kn + sc*8);
      rv1 = *(const u32x4*)(vbase + (size_t)srow*SPAD + kn + (sc+4)*8);
    }
    float p[2][2][4];
    bool tail = (k0 + 64 > SK);
    #pragma unroll
    for (int h = 0; h < 2; ++h){
      #pragma unroll
      for (int ns = 0; ns < 2; ++ns){
        f32x4 zf = (f32x4){0.f,0.f,0.f,0.f};
        #pragma unroll
        for (int ec = 0; ec < 2; ++ec){
          bf16x8 bkf = *(const bf16x8*)(Ks + (h*32 + 2*l16 + ns)*KSTR + ec*32 + quad*8);
          zf = __builtin_amdgcn_mfma_f32_16x16x32_bf16(aq[ec], bkf, zf, 0,0,0);
        }
        bool valid = !tail || (k0 + h*32 + 2*l16 + ns) < SK;
        #pragma unroll
        for (int rg = 0; rg < 4; ++rg) p[h][ns][rg] = valid ? __expf(zf[rg]) : 0.f;
      }
    }
    unsigned short* Pw = Ps + w*16*KSTR;
    #pragma unroll
    for (int rg = 0; rg < 4; ++rg){
      rsum[rg] += (p[0][0][rg] + p[0][1][rg]) + (p[1][0][rg] + p[1][1][rg]);
      *(unsigned int*)(Pw + (quad*4+rg)*KSTR      + 2*l16) = pk_bf16(p[0][0][rg], p[0][1][rg]);
      *(unsigned int*)(Pw + (quad*4+rg)*KSTR + 32 + 2*l16) = pk_bf16(p[1][0][rg], p[1][1][rg]);
    }
    #pragma unroll
    for (int kc = 0; kc < 2; ++kc){
      bf16x8 ap = *(const bf16x8*)(Pw + l16*KSTR + kc*32 + quad*8);
      #pragma unroll
      for (int nc = 0; nc < 4; ++nc){
        bf16x8 bvf = *(const bf16x8*)(Vs + (nc*16 + l16)*KSTR + kc*32 + quad*8);
        o[nc] = __builtin_amdgcn_mfma_f32_16x16x32_bf16(ap, bvf, o[nc], 0,0,0);
      }
    }
  }
  #pragma unroll
  for (int rg = 0; rg < 4; ++rg){
    float s = rsum[rg];
    #pragma unroll
    for (int off = 8; off >= 1; off >>= 1) s += __shfl_xor(s, off);
    rsum[rg] = s;
  }
  int b = bh / HH, h = bh % HH;
  #pragma unroll
  for (int rg = 0; rg < 4; ++rg){
    int q = q0 + quad*4 + rg;
    if (q >= SS) continue;
    float inv = 1.f / rsum[rg];
    unsigned short* dst = zo + ((size_t)b*SS + q)*384 + h*64;
    #pragma unroll
    for (int nc = 0; nc < 4; ++nc) dst[nc*16 + l16] = f2bf(o[nc][rg]*inv);
  }
}

// ---------------- launch ----------------
extern "C" void kernel_launch(void* const* d_in, const int* in_sizes, int n_in,
                              void* d_out, int out_size, void* d_ws, size_t ws_size,
                              hipStream_t stream){
  const float* x  = (const float*)d_in[0];
  const float* wq = (const float*)d_in[1];
  const float* bq = (const float*)d_in[2];
  const float* wk = (const float*)d_in[3];
  const float* bk = (const float*)d_in[4];
  const float* wv = (const float*)d_in[5];
  const float* bv = (const float*)d_in[6];
  const float* wo = (const float*)d_in[7];
  const float* bo = (const float*)d_in[8];
  const int* kpat = (const int*)d_in[10];
  float* out = (float*)d_out;
  float* out_agg = out + (size_t)MROWS*DD;

  char* ws = (char*)d_ws;
  unsigned short* xb  = (unsigned short*)(ws);
  unsigned short* wbT = (unsigned short*)(ws +  8441856);
  unsigned short* woT = (unsigned short*)(ws +  9326592);
  unsigned short* qg  = (unsigned short*)(ws +  9621504);
  unsigned short* kg  = (unsigned short*)(ws + 18063360);
  unsigned short* vt  = (unsigned short*)(ws + 26505216);
  unsigned short* zo  = (unsigned short*)(ws + 34959360);
  float* xbar         = (float*)(ws + 43401216);
  float* qbar         = (float*)(ws + 43413504);
  (void)in_sizes; (void)n_in; (void)out_size; (void)ws_size;

  hipMemsetAsync(xbar, 0, BB*DD*sizeof(float), stream);
  k_conv_x<<<(MROWS*DD/4 + 255)/256, 256, 0, stream>>>(x, xb, MROWS*DD/4);
  k_conv_w<<<((1152*384 + 384*384) + 255)/256, 256, 0, stream>>>(wq, wk, wv, wo, wbT, woT);
  k_xbar<<<BB*11, DD, 0, stream>>>(x, xbar);
  k_qbar<<<BB, DD, 0, stream>>>(xbar, wq, bq, qbar);
  k_gemm<0><<<86*9, 256, 0, stream>>>(xb, wbT, bq, bk, bv, qg, kg, vt, nullptr);
  k_attn<<<BB*HH*22, 256, 0, stream>>>(qg, kg, vt, zo, kpat);
  k_agg<<<BB*6, 256, 0, stream>>>(qbar, kg, out_agg);
  k_gemm<1><<<86*3, 256, 0, stream>>>(zo, woT, bo, nullptr, nullptr, nullptr, nullptr, nullptr, out);
}

// Round 4
// 228.900 us; speedup vs baseline: 1.0427x; 1.0427x over previous
//
#include <hip/hip_runtime.h>
#include <stdint.h>

#define BB 8
#define SS 1374
#define DD 384
#define HH 6
#define HDIM 64
#define MROWS (BB*SS)   // 10992
#define NPFX 5
#define SPAD 1376       // padded S for vt rows (16B-aligned rows)

typedef __attribute__((ext_vector_type(8))) short bf16x8;
typedef __attribute__((ext_vector_type(4))) float f32x4;
typedef __attribute__((ext_vector_type(2))) unsigned int u32x2;
typedef __attribute__((ext_vector_type(4))) unsigned int u32x4;

__device__ __forceinline__ unsigned short f2bf(float f){
  union { float f; unsigned int u; } v; v.f = f;
  return (unsigned short)((v.u + 0x7FFFu + ((v.u >> 16) & 1u)) >> 16);
}
__device__ __forceinline__ float bf2f(unsigned short b){
  union { float f; unsigned int u; } v; v.u = ((unsigned int)b) << 16; return v.f;
}
__device__ __forceinline__ unsigned int pk_bf16(float a, float b){
#if __has_builtin(__builtin_amdgcn_cvt_pk_bf16_f32)
  typedef __attribute__((ext_vector_type(2))) __bf16 bfv2;
  bfv2 p = __builtin_amdgcn_cvt_pk_bf16_f32(a, b);
  union { bfv2 v; unsigned int u; } c; c.v = p; return c.u;
#else
  return (unsigned int)f2bf(a) | ((unsigned int)f2bf(b) << 16);
#endif
}

// ---------------- prep kernels ----------------
__global__ void k_conv_x(const float* __restrict__ x, unsigned short* __restrict__ xb, int n4){
  int i = blockIdx.x*blockDim.x + threadIdx.x;
  if (i >= n4) return;
  f32x4 v = *(const f32x4*)(x + (size_t)i*4);
  u32x2 o; o[0] = pk_bf16(v[0], v[1]); o[1] = pk_bf16(v[2], v[3]);
  *(u32x2*)(xb + (size_t)i*4) = o;
}

__global__ void k_conv_w(const float* __restrict__ wq, const float* __restrict__ wk,
                         const float* __restrict__ wv, const float* __restrict__ wo,
                         unsigned short* __restrict__ wbT, unsigned short* __restrict__ woT){
  int i = blockIdx.x*blockDim.x + threadIdx.x;
  if (i < 1152*384){
    int n = i / 384, d = i % 384;
    const float* w = (n < 384) ? wq : (n < 768) ? wk : wv;
    wbT[i] = f2bf(w[(size_t)d*384 + (n % 384)]);
  } else if (i < 1152*384 + 384*384){
    int j = i - 1152*384;
    int n = j / 384, k = j % 384;
    woT[j] = f2bf(wo[(size_t)k*384 + n]);
  }
}

__global__ void k_xbar(const float* __restrict__ x, float* __restrict__ xbar){
  int b = blockIdx.x / 11, ch = blockIdx.x % 11;
  int d = threadIdx.x;
  int s0 = ch*128, s1 = s0 + 128; if (s1 > SS) s1 = SS;
  float acc = 0.f;
  for (int s = s0; s < s1; ++s){
    float w = (s == 0) ? (1.f/3.f) : (s < 5) ? (1.f/12.f) : (1.f/4107.f);
    acc += w * x[((size_t)b*SS + s)*DD + d];
  }
  atomicAdd(&xbar[b*DD + d], acc);
}

__global__ void k_qbar(const float* __restrict__ xbar, const float* __restrict__ wq,
                       const float* __restrict__ bq, float* __restrict__ qbar){
  __shared__ float xs[DD];
  int b = blockIdx.x, t = threadIdx.x;
  xs[t] = xbar[b*DD + t];
  __syncthreads();
  float acc = bq[t];
  for (int d = 0; d < DD; ++d) acc += xs[d]*wq[(size_t)d*384 + t];
  qbar[b*384 + t] = acc;
}

__global__ void k_agg(const float* __restrict__ qbar, const unsigned short* __restrict__ kg,
                      float* __restrict__ out_agg){
  __shared__ float qs[384];
  int b = blockIdx.x / 6, sb = blockIdx.x % 6;
  int t = threadIdx.x;
  for (int i = t; i < 384; i += 256) qs[i] = qbar[b*384 + i];
  __syncthreads();
  int s = sb*256 + t;
  if (s >= SS) return;
  float acc = 0.f;
  for (int h = 0; h < HH; ++h){
    const unsigned short* kr = kg + (((size_t)(b*HH + h))*SS + s)*64;
    const float* qh = qs + h*64;
    for (int c = 0; c < 8; ++c){
      u32x4 v = *(const u32x4*)(kr + c*8);
      #pragma unroll
      for (int j = 0; j < 4; ++j){
        unsigned int u = v[j];
        acc += qh[c*8 + 2*j]     * bf2f((unsigned short)(u & 0xFFFFu));
        acc += qh[c*8 + 2*j + 1] * bf2f((unsigned short)(u >> 16));
      }
    }
  }
  out_agg[b*SS + s] = acc * (1.f/48.f);
}

// ---------------- MFMA GEMM: TMx128 tile, BK=32, register staging + prefetch, padded LDS ----------------
// MODE 0 (TM=128): C(10992x1152) = xb * wbT^T -> qg(*1/8)/kg (B,H,S,64), vt (B,H,64,SPAD), +bias, bf16
// MODE 1 (TM=64):  C(10992x384)  = zo * woT^T -> out fp32 + bo
template<int TM, int MODE>
__global__ __launch_bounds__(256) void k_gemm(
    const unsigned short* __restrict__ A, const unsigned short* __restrict__ Bt,
    const float* __restrict__ b0, const float* __restrict__ b1, const float* __restrict__ b2,
    unsigned short* __restrict__ qg, unsigned short* __restrict__ kgp,
    unsigned short* __restrict__ vt, float* __restrict__ out)
{
  constexpr int MT = (MROWS + TM - 1) / TM;
  constexpr int RF = TM/32;          // row frags per wave
  int mt = blockIdx.x % MT, nt = blockIdx.x / MT;
  const int t = threadIdx.x;
  const int w = t >> 6, lane = t & 63, quad = lane >> 4, l16 = lane & 15;
  const int wm = w >> 1, wn = w & 1;
  __shared__ unsigned short As[TM*40];    // stride 40 shorts (80B) -> balanced banks
  __shared__ unsigned short Bs[128*40];
  f32x4 acc[RF][4];
  #pragma unroll
  for (int i=0;i<RF;i++)
    #pragma unroll
    for (int j=0;j<4;j++) acc[i][j] = (f32x4){0.f,0.f,0.f,0.f};
  const int m0 = mt*TM, n0 = nt*128;

  // staging mapping (BK=32 shorts = 4 b128 chunks per row)
  // A: TM=128 -> 2 chunks/thread (row=t>>1, chunks (t&1)*2+{0,1}); TM=64 -> 1 chunk (row=t>>2, chunk t&3)
  int arow, ac;            // ac in shorts
  if (TM == 128){ arow = t >> 1; ac = (t & 1) * 16; }
  else          { arow = t >> 2; ac = (t & 3) * 8;  }
  int ga = m0 + arow; if (ga > MROWS-1) ga = MROWS-1;
  const unsigned short* ap = A + (size_t)ga*384 + ac;
  // B: always 128 rows -> 2 chunks/thread
  const int brow = t >> 1, bc = (t & 1) * 16;
  const unsigned short* bp = Bt + (size_t)(n0 + brow)*384 + bc;

  // prefetch tile 0
  u32x4 ra0, ra1, rb0, rb1;
  if (TM == 128){ ra0 = *(const u32x4*)(ap); ra1 = *(const u32x4*)(ap + 8); }
  else          { ra0 = *(const u32x4*)(ap); }
  rb0 = *(const u32x4*)(bp); rb1 = *(const u32x4*)(bp + 8);

  for (int kc = 0; kc < 12; ++kc){
    __syncthreads();                       // prev tile fully consumed
    if (TM == 128){
      *(u32x4*)(As + arow*40 + ac)     = ra0;
      *(u32x4*)(As + arow*40 + ac + 8) = ra1;
    } else {
      *(u32x4*)(As + arow*40 + ac) = ra0;
    }
    *(u32x4*)(Bs + brow*40 + bc)     = rb0;
    *(u32x4*)(Bs + brow*40 + bc + 8) = rb1;
    __syncthreads();                       // tile ready
    if (kc + 1 < 12){
      int kn = (kc+1)*32;
      if (TM == 128){ ra0 = *(const u32x4*)(ap + kn); ra1 = *(const u32x4*)(ap + kn + 8); }
      else          { ra0 = *(const u32x4*)(ap + kn); }
      rb0 = *(const u32x4*)(bp + kn); rb1 = *(const u32x4*)(bp + kn + 8);
    }
    bf16x8 af[RF], bfr[4];
    #pragma unroll
    for (int rf = 0; rf < RF; ++rf)
      af[rf] = *(const bf16x8*)(As + (wm*(TM/2) + rf*16 + l16)*40 + quad*8);
    #pragma unroll
    for (int cf = 0; cf < 4; ++cf)
      bfr[cf] = *(const bf16x8*)(Bs + (wn*64 + cf*16 + l16)*40 + quad*8);
    #pragma unroll
    for (int rf = 0; rf < RF; ++rf)
      #pragma unroll
      for (int cf = 0; cf < 4; ++cf)
        acc[rf][cf] = __builtin_amdgcn_mfma_f32_16x16x32_bf16(af[rf], bfr[cf], acc[rf][cf], 0,0,0);
  }
  // epilogue
  #pragma unroll
  for (int cf = 0; cf < 4; ++cf){
    int n = n0 + wn*64 + cf*16 + l16;
    int mat = n / 384, he = n % 384, h = he >> 6, e = he & 63;
    float bias = (MODE==0) ? ((mat==0 ? b0 : (mat==1 ? b1 : b2))[he]) : b0[n];
    float vsc = (MODE==0 && mat==0) ? 0.125f : 1.f;
    #pragma unroll
    for (int rf = 0; rf < RF; ++rf){
      int rbase = m0 + wm*(TM/2) + rf*16 + quad*4;
      if (MODE == 1){
        #pragma unroll
        for (int r4 = 0; r4 < 4; ++r4){
          int rr = rbase + r4;
          if (rr < MROWS) out[(size_t)rr*384 + n] = acc[rf][cf][r4] + bias;
        }
      } else if (mat < 2){
        unsigned short* dst = (mat==0) ? qg : kgp;
        #pragma unroll
        for (int r4 = 0; r4 < 4; ++r4){
          int rr = rbase + r4;
          if (rr < MROWS){
            int b = rr / SS, s = rr % SS;
            dst[(((size_t)(b*HH + h))*SS + s)*64 + e] = f2bf((acc[rf][cf][r4] + bias)*vsc);
          }
        }
      } else {
        #pragma unroll
        for (int p = 0; p < 2; ++p){
          int rr = rbase + p*2;
          if (rr < MROWS){
            int b = rr / SS, s = rr % SS;
            *(unsigned int*)(vt + ((size_t)(b*HH + h)*64 + e)*SPAD + s) =
                pk_bf16(acc[rf][cf][p*2] + bias, acc[rf][cf][p*2+1] + bias);
          }
        }
      }
    }
  }
}

// ---------------- flash attention (no online max: |z| << 80 so exp is safe) ----------------
#define KSTR 72
__global__ __launch_bounds__(256) void k_attn(
    const unsigned short* __restrict__ qg, const unsigned short* __restrict__ kg,
    const unsigned short* __restrict__ vt, unsigned short* __restrict__ zo,
    const int* __restrict__ kpat)
{
  const int QB = (SS + 63)/64; // 22
  int qb = blockIdx.x % QB, bh = blockIdx.x / QB;
  int t = threadIdx.x, w = t >> 6, lane = t & 63, quad = lane >> 4, l16 = lane & 15;
  int SK = NPFX + kpat[0]; if (SK > SS) SK = SS; if (SK < 1) SK = 1;
  int niter = (SK + 63) >> 6;
  __shared__ unsigned short Ks[64*KSTR];
  __shared__ unsigned short Vs[64*KSTR];
  __shared__ unsigned short Ps[4*16*KSTR];
  int q0 = qb*64 + w*16;
  bf16x8 aq[2];
  {
    int qrow = q0 + l16;
    if (qrow < SS){
      const unsigned short* p = qg + ((size_t)bh*SS + qrow)*64;
      aq[0] = *(const bf16x8*)(p + quad*8);
      aq[1] = *(const bf16x8*)(p + 32 + quad*8);
    } else {
      bf16x8 z8 = {0,0,0,0,0,0,0,0};
      aq[0] = z8; aq[1] = z8;
    }
  }
  f32x4 o[4];
  #pragma unroll
  for (int i=0;i<4;i++) o[i] = (f32x4){0.f,0.f,0.f,0.f};
  float rsum[4] = {0.f,0.f,0.f,0.f};

  const int srow = t >> 2, sc = t & 3;
  const unsigned short* kbase = kg + ((size_t)bh*SS)*64;
  const unsigned short* vbase = vt + ((size_t)bh*64)*SPAD;
  u32x4 rk0, rk1, rv0, rv1;
  rk0 = *(const u32x4*)(kbase + (size_t)srow*64 + sc*8);
  rk1 = *(const u32x4*)(kbase + (size_t)srow*64 + (sc+4)*8);
  rv0 = *(const u32x4*)(vbase + (size_t)srow*SPAD + sc*8);
  rv1 = *(const u32x4*)(vbase + (size_t)srow*SPAD + (sc+4)*8);

  for (int it = 0; it < niter; ++it){
    int k0 = it*64;
    __syncthreads();
    *(u32x4*)(Ks + srow*KSTR + sc*8)     = rk0;
    *(u32x4*)(Ks + srow*KSTR + (sc+4)*8) = rk1;
    *(u32x4*)(Vs + srow*KSTR + sc*8)     = rv0;
    *(u32x4*)(Vs + srow*KSTR + (sc+4)*8) = rv1;
    __syncthreads();
    if (it + 1 < niter){
      int kn = k0 + 64;
      rk0 = *(const u32x4*)(kbase + (size_t)(kn + srow)*64 + sc*8);
      rk1 = *(const u32x4*)(kbase + (size_t)(kn + srow)*64 + (sc+4)*8);
      rv0 = *(const u32x4*)(vbase + (size_t)srow*SPAD + kn + sc*8);
      rv1 = *(const u32x4*)(vbase + (size_t)srow*SPAD + kn + (sc+4)*8);
    }
    float p[2][2][4];
    bool tail = (k0 + 64 > SK);
    #pragma unroll
    for (int h = 0; h < 2; ++h){
      #pragma unroll
      for (int ns = 0; ns < 2; ++ns){
        f32x4 zf = (f32x4){0.f,0.f,0.f,0.f};
        #pragma unroll
        for (int ec = 0; ec < 2; ++ec){
          bf16x8 bkf = *(const bf16x8*)(Ks + (h*32 + 2*l16 + ns)*KSTR + ec*32 + quad*8);
          zf = __builtin_amdgcn_mfma_f32_16x16x32_bf16(aq[ec], bkf, zf, 0,0,0);
        }
        bool valid = !tail || (k0 + h*32 + 2*l16 + ns) < SK;
        #pragma unroll
        for (int rg = 0; rg < 4; ++rg) p[h][ns][rg] = valid ? __expf(zf[rg]) : 0.f;
      }
    }
    unsigned short* Pw = Ps + w*16*KSTR;
    #pragma unroll
    for (int rg = 0; rg < 4; ++rg){
      rsum[rg] += (p[0][0][rg] + p[0][1][rg]) + (p[1][0][rg] + p[1][1][rg]);
      *(unsigned int*)(Pw + (quad*4+rg)*KSTR      + 2*l16) = pk_bf16(p[0][0][rg], p[0][1][rg]);
      *(unsigned int*)(Pw + (quad*4+rg)*KSTR + 32 + 2*l16) = pk_bf16(p[1][0][rg], p[1][1][rg]);
    }
    #pragma unroll
    for (int kc = 0; kc < 2; ++kc){
      bf16x8 ap = *(const bf16x8*)(Pw + l16*KSTR + kc*32 + quad*8);
      #pragma unroll
      for (int nc = 0; nc < 4; ++nc){
        bf16x8 bvf = *(const bf16x8*)(Vs + (nc*16 + l16)*KSTR + kc*32 + quad*8);
        o[nc] = __builtin_amdgcn_mfma_f32_16x16x32_bf16(ap, bvf, o[nc], 0,0,0);
      }
    }
  }
  #pragma unroll
  for (int rg = 0; rg < 4; ++rg){
    float s = rsum[rg];
    #pragma unroll
    for (int off = 8; off >= 1; off >>= 1) s += __shfl_xor(s, off);
    rsum[rg] = s;
  }
  int b = bh / HH, h = bh % HH;
  #pragma unroll
  for (int rg = 0; rg < 4; ++rg){
    int q = q0 + quad*4 + rg;
    if (q >= SS) continue;
    float inv = 1.f / rsum[rg];
    unsigned short* dst = zo + ((size_t)b*SS + q)*384 + h*64;
    #pragma unroll
    for (int nc = 0; nc < 4; ++nc) dst[nc*16 + l16] = f2bf(o[nc][rg]*inv);
  }
}

// ---------------- launch ----------------
extern "C" void kernel_launch(void* const* d_in, const int* in_sizes, int n_in,
                              void* d_out, int out_size, void* d_ws, size_t ws_size,
                              hipStream_t stream){
  const float* x  = (const float*)d_in[0];
  const float* wq = (const float*)d_in[1];
  const float* bq = (const float*)d_in[2];
  const float* wk = (const float*)d_in[3];
  const float* bk = (const float*)d_in[4];
  const float* wv = (const float*)d_in[5];
  const float* bv = (const float*)d_in[6];
  const float* wo = (const float*)d_in[7];
  const float* bo = (const float*)d_in[8];
  const int* kpat = (const int*)d_in[10];
  float* out = (float*)d_out;
  float* out_agg = out + (size_t)MROWS*DD;

  char* ws = (char*)d_ws;
  unsigned short* xb  = (unsigned short*)(ws);
  unsigned short* wbT = (unsigned short*)(ws +  8441856);
  unsigned short* woT = (unsigned short*)(ws +  9326592);
  unsigned short* qg  = (unsigned short*)(ws +  9621504);
  unsigned short* kg  = (unsigned short*)(ws + 18063360);
  unsigned short* vt  = (unsigned short*)(ws + 26505216);
  unsigned short* zo  = (unsigned short*)(ws + 34959360);
  float* xbar         = (float*)(ws + 43401216);
  float* qbar         = (float*)(ws + 43413504);
  (void)in_sizes; (void)n_in; (void)out_size; (void)ws_size;

  hipMemsetAsync(xbar, 0, BB*DD*sizeof(float), stream);
  k_conv_x<<<(MROWS*DD/4 + 255)/256, 256, 0, stream>>>(x, xb, MROWS*DD/4);
  k_conv_w<<<((1152*384 + 384*384) + 255)/256, 256, 0, stream>>>(wq, wk, wv, wo, wbT, woT);
  k_xbar<<<BB*11, DD, 0, stream>>>(x, xbar);
  k_qbar<<<BB, DD, 0, stream>>>(xbar, wq, bq, qbar);
  k_gemm<128,0><<<86*9, 256, 0, stream>>>(xb, wbT, bq, bk, bv, qg, kg, vt, nullptr);
  k_attn<<<BB*HH*22, 256, 0, stream>>>(qg, kg, vt, zo, kpat);
  k_agg<<<BB*6, 256, 0, stream>>>(qbar, kg, out_agg);
  k_gemm<64,1><<<172*3, 256, 0, stream>>>(zo, woT, bo, nullptr, nullptr, nullptr, nullptr, nullptr, out);
}

// Round 5
// 212.325 us; speedup vs baseline: 1.1241x; 1.0781x over previous
//
#include <hip/hip_runtime.h>
#include <stdint.h>

#define BB 8
#define SS 1374
#define DD 384
#define HH 6
#define HDIM 64
#define MROWS (BB*SS)   // 10992
#define NPFX 5
#define SPAD 1376       // padded S for vt rows

typedef __attribute__((ext_vector_type(8))) short bf16x8;
typedef __attribute__((ext_vector_type(4))) float f32x4;
typedef __attribute__((ext_vector_type(2))) unsigned int u32x2;
typedef __attribute__((ext_vector_type(4))) unsigned int u32x4;
typedef u32x4 __attribute__((aligned(4))) u32x4_u;   // dword-aligned global vector store

__device__ __forceinline__ unsigned short f2bf(float f){
  union { float f; unsigned int u; } v; v.f = f;
  return (unsigned short)((v.u + 0x7FFFu + ((v.u >> 16) & 1u)) >> 16);
}
__device__ __forceinline__ float bf2f(unsigned short b){
  union { float f; unsigned int u; } v; v.u = ((unsigned int)b) << 16; return v.f;
}
__device__ __forceinline__ unsigned int pk_bf16(float a, float b){
#if __has_builtin(__builtin_amdgcn_cvt_pk_bf16_f32)
  typedef __attribute__((ext_vector_type(2))) __bf16 bfv2;
  bfv2 p = __builtin_amdgcn_cvt_pk_bf16_f32(a, b);
  union { bfv2 v; unsigned int u; } c; c.v = p; return c.u;
#else
  return (unsigned int)f2bf(a) | ((unsigned int)f2bf(b) << 16);
#endif
}

// ---------------- prep kernels ----------------
__global__ void k_conv_x(const float* __restrict__ x, unsigned short* __restrict__ xb, int n4){
  int i = blockIdx.x*blockDim.x + threadIdx.x;
  if (i >= n4) return;
  f32x4 v = *(const f32x4*)(x + (size_t)i*4);
  u32x2 o; o[0] = pk_bf16(v[0], v[1]); o[1] = pk_bf16(v[2], v[3]);
  *(u32x2*)(xb + (size_t)i*4) = o;
}

__global__ void k_conv_w(const float* __restrict__ wq, const float* __restrict__ wk,
                         const float* __restrict__ wv, const float* __restrict__ wo,
                         unsigned short* __restrict__ wbT, unsigned short* __restrict__ woT){
  int i = blockIdx.x*blockDim.x + threadIdx.x;
  if (i < 1152*384){
    int n = i / 384, d = i % 384;
    const float* w = (n < 384) ? wq : (n < 768) ? wk : wv;
    wbT[i] = f2bf(w[(size_t)d*384 + (n % 384)]);
  } else if (i < 1152*384 + 384*384){
    int j = i - 1152*384;
    int n = j / 384, k = j % 384;
    woT[j] = f2bf(wo[(size_t)k*384 + n]);
  }
}

__global__ void k_xbar(const float* __restrict__ x, float* __restrict__ xbar){
  int b = blockIdx.x / 11, ch = blockIdx.x % 11;
  int d = threadIdx.x;
  int s0 = ch*128, s1 = s0 + 128; if (s1 > SS) s1 = SS;
  float acc = 0.f;
  for (int s = s0; s < s1; ++s){
    float w = (s == 0) ? (1.f/3.f) : (s < 5) ? (1.f/12.f) : (1.f/4107.f);
    acc += w * x[((size_t)b*SS + s)*DD + d];
  }
  atomicAdd(&xbar[b*DD + d], acc);
}

__global__ void k_qbar(const float* __restrict__ xbar, const float* __restrict__ wq,
                       const float* __restrict__ bq, float* __restrict__ qbar){
  __shared__ float xs[DD];
  int b = blockIdx.x, t = threadIdx.x;
  xs[t] = xbar[b*DD + t];
  __syncthreads();
  float acc = bq[t];
  for (int d = 0; d < DD; ++d) acc += xs[d]*wq[(size_t)d*384 + t];
  qbar[b*384 + t] = acc;
}

__global__ void k_agg(const float* __restrict__ qbar, const unsigned short* __restrict__ kg,
                      float* __restrict__ out_agg){
  __shared__ float qs[384];
  int b = blockIdx.x / 6, sb = blockIdx.x % 6;
  int t = threadIdx.x;
  for (int i = t; i < 384; i += 256) qs[i] = qbar[b*384 + i];
  __syncthreads();
  int s = sb*256 + t;
  if (s >= SS) return;
  float acc = 0.f;
  for (int h = 0; h < HH; ++h){
    const unsigned short* kr = kg + (((size_t)(b*HH + h))*SS + s)*64;
    const float* qh = qs + h*64;
    for (int c = 0; c < 8; ++c){
      u32x4 v = *(const u32x4*)(kr + c*8);
      #pragma unroll
      for (int j = 0; j < 4; ++j){
        unsigned int u = v[j];
        acc += qh[c*8 + 2*j]     * bf2f((unsigned short)(u & 0xFFFFu));
        acc += qh[c*8 + 2*j + 1] * bf2f((unsigned short)(u >> 16));
      }
    }
  }
  out_agg[b*SS + s] = acc * (1.f/48.f);
}

// ---------------- MFMA GEMM: 128x64 tile, BK=64 (6 iters), reg prefetch, coalesced epilogue ----
// MODE 0: C(10992x1152) = xb * wbT^T -> qg(*1/8)/kg (B,H,S,64), vt (B,H,64,SPAD), +bias, bf16
// MODE 1: C(10992x384)  = zo * woT^T -> out fp32 + bo
template<int MODE>
__global__ __launch_bounds__(256) void k_gemm(
    const unsigned short* __restrict__ A, const unsigned short* __restrict__ Bt,
    const float* __restrict__ b0, const float* __restrict__ b1, const float* __restrict__ b2,
    unsigned short* __restrict__ qg, unsigned short* __restrict__ kgp,
    unsigned short* __restrict__ vt, float* __restrict__ out)
{
  int mt = blockIdx.x % 86, nt = blockIdx.x / 86;
  const int t = threadIdx.x;
  const int w = t >> 6, lane = t & 63, quad = lane >> 4, l16 = lane & 15;
  const int wm = w >> 1, wn = w & 1;      // waves 2x2 over (128 rows, 64 cols)
  constexpr int SMEM_SH = (MODE==0) ? 13824 : 17408;
  __shared__ unsigned short smem[SMEM_SH];
  unsigned short* As = smem;              // [128][72]
  unsigned short* Bs = smem + 9216;       // [64][72]
  f32x4 acc[4][2];
  #pragma unroll
  for (int i=0;i<4;i++){ acc[i][0] = (f32x4){0,0,0,0}; acc[i][1] = (f32x4){0,0,0,0}; }
  const int m0 = mt*128, n0 = nt*64;

  // A staging: row = t>>1 (128 rows), 64B contiguous: kbase = (t&1)*32 shorts
  const int ar = t >> 1, akb = (t & 1) * 32;
  int ga = m0 + ar; if (ga > MROWS-1) ga = MROWS-1;
  const unsigned short* ap = A + (size_t)ga*384 + akb;
  // B staging: row = t>>2 (64 rows), 32B contiguous: kbase = (t&3)*16 shorts
  const int br = t >> 2, bkb = (t & 3) * 16;
  const unsigned short* bp = Bt + (size_t)(n0 + br)*384 + bkb;

  u32x4 ra[4], rb[2];
  #pragma unroll
  for (int i=0;i<4;i++) ra[i] = *(const u32x4*)(ap + i*8);
  rb[0] = *(const u32x4*)(bp); rb[1] = *(const u32x4*)(bp + 8);

  for (int kc = 0; kc < 6; ++kc){
    __syncthreads();
    #pragma unroll
    for (int i=0;i<4;i++) *(u32x4*)(As + ar*72 + akb + i*8) = ra[i];
    *(u32x4*)(Bs + br*72 + bkb)     = rb[0];
    *(u32x4*)(Bs + br*72 + bkb + 8) = rb[1];
    __syncthreads();
    if (kc + 1 < 6){
      int kn = (kc+1)*64;
      #pragma unroll
      for (int i=0;i<4;i++) ra[i] = *(const u32x4*)(ap + kn + i*8);
      rb[0] = *(const u32x4*)(bp + kn); rb[1] = *(const u32x4*)(bp + kn + 8);
    }
    #pragma unroll
    for (int kh = 0; kh < 2; ++kh){
      bf16x8 af[4], bfr[2];
      #pragma unroll
      for (int rf = 0; rf < 4; ++rf)
        af[rf] = *(const bf16x8*)(As + (wm*64 + rf*16 + l16)*72 + kh*32 + quad*8);
      #pragma unroll
      for (int cf = 0; cf < 2; ++cf)
        bfr[cf] = *(const bf16x8*)(Bs + (wn*32 + cf*16 + l16)*72 + kh*32 + quad*8);
      #pragma unroll
      for (int rf = 0; rf < 4; ++rf)
        #pragma unroll
        for (int cf = 0; cf < 2; ++cf)
          acc[rf][cf] = __builtin_amdgcn_mfma_f32_16x16x32_bf16(af[rf], bfr[cf], acc[rf][cf], 0,0,0);
    }
  }

  // ---- coalesced epilogue (restage via LDS) ----
  const int b0r = m0 / SS, s0r = m0 % SS;   // block-uniform; at most one wrap inside block
  __syncthreads();                          // all waves done reading As/Bs
  if (MODE == 1){
    float* CsF = (float*)smem;              // [128][68]
    #pragma unroll
    for (int cf = 0; cf < 2; ++cf){
      int e = wn*32 + cf*16 + l16;
      float bias = b0[n0 + e];
      #pragma unroll
      for (int rf = 0; rf < 4; ++rf){
        int rr = wm*64 + rf*16 + quad*4;
        #pragma unroll
        for (int r4 = 0; r4 < 4; ++r4)
          CsF[(rr + r4)*68 + e] = acc[rf][cf][r4] + bias;
      }
    }
    __syncthreads();
    #pragma unroll
    for (int p = 0; p < 8; ++p){
      int r = p*16 + (t >> 4), c = t & 15;
      int rr = m0 + r;
      if (rr < MROWS){
        f32x4 v = *(const f32x4*)(CsF + r*68 + c*4);
        *(f32x4*)(out + (size_t)rr*384 + n0 + c*4) = v;
      }
    }
  } else {
    const int mat = nt / 6, h = nt - mat*6;     // one (tensor, head) per block
    const float* bvp = (mat==0) ? b0 : (mat==1) ? b1 : b2;
    const float vsc = (mat==0) ? 0.125f : 1.f;  // fold 1/sqrt(64) into q
    if (mat < 2){
      unsigned short* Cs = As;                  // [128][72]
      unsigned short* dst = (mat==0) ? qg : kgp;
      #pragma unroll
      for (int cf = 0; cf < 2; ++cf){
        int e = wn*32 + cf*16 + l16;
        float bias = bvp[h*64 + e];
        #pragma unroll
        for (int rf = 0; rf < 4; ++rf){
          int rr = wm*64 + rf*16 + quad*4;
          #pragma unroll
          for (int r4 = 0; r4 < 4; ++r4)
            Cs[(rr + r4)*72 + e] = f2bf((acc[rf][cf][r4] + bias)*vsc);
        }
      }
      __syncthreads();
      #pragma unroll
      for (int p = 0; p < 4; ++p){
        int r = p*32 + (t >> 3), c = t & 7;
        int rr = m0 + r;
        if (rr < MROWS){
          int s = s0r + r, bb = b0r;
          if (s >= SS){ s -= SS; ++bb; }
          u32x4 v = *(const u32x4*)(Cs + r*72 + c*8);
          *(u32x4*)(dst + (((size_t)(bb*HH + h))*SS + s)*64 + c*8) = v;
        }
      }
    } else {
      unsigned short* CsV = As;                 // [64 e][136 s-pad]
      #pragma unroll
      for (int cf = 0; cf < 2; ++cf){
        int e = wn*32 + cf*16 + l16;
        float bias = bvp[h*64 + e];
        #pragma unroll
        for (int rf = 0; rf < 4; ++rf){
          int rr = wm*64 + rf*16 + quad*4;
          #pragma unroll
          for (int p = 0; p < 2; ++p)
            *(unsigned int*)(CsV + e*136 + rr + p*2) =
                pk_bf16(acc[rf][cf][p*2] + bias, acc[rf][cf][p*2+1] + bias);
        }
      }
      __syncthreads();
      const bool nowrap = (s0r + 127 < SS) && (m0 + 127 < MROWS);
      if (nowrap){
        int e = t >> 2;
        unsigned short* vrow = vt + ((size_t)(b0r*HH + h)*64 + e)*SPAD + s0r;
        #pragma unroll
        for (int i = 0; i < 4; ++i){
          int c = (t & 3)*4 + i;
          u32x4 v = *(const u32x4*)(CsV + e*136 + c*8);
          *(u32x4_u*)(vrow + c*8) = v;
        }
      } else {
        for (int idx = t; idx < 64*64; idx += 256){
          int e = idx >> 6, sp = (idx & 63)*2;
          int rr = m0 + sp;
          if (rr < MROWS){
            int s = s0r + sp, bb = b0r;
            if (s >= SS){ s -= SS; ++bb; }
            *(unsigned int*)(vt + ((size_t)(bb*HH + h)*64 + e)*SPAD + s) =
                *(const unsigned int*)(CsV + e*136 + sp);
          }
        }
      }
    }
  }
}

// ---------------- flash attention (no online max: |z| << 80 so exp is safe) ----------------
#define KSTR 72
__global__ __launch_bounds__(256) void k_attn(
    const unsigned short* __restrict__ qg, const unsigned short* __restrict__ kg,
    const unsigned short* __restrict__ vt, unsigned short* __restrict__ zo,
    const int* __restrict__ kpat)
{
  const int QB = (SS + 63)/64; // 22
  int qb = blockIdx.x % QB, bh = blockIdx.x / QB;
  int t = threadIdx.x, w = t >> 6, lane = t & 63, quad = lane >> 4, l16 = lane & 15;
  int SK = NPFX + kpat[0]; if (SK > SS) SK = SS; if (SK < 1) SK = 1;
  int niter = (SK + 63) >> 6;
  __shared__ unsigned short Ks[64*KSTR];
  __shared__ unsigned short Vs[64*KSTR];
  __shared__ unsigned short Ps[4*16*KSTR];
  int q0 = qb*64 + w*16;
  bf16x8 aq[2];
  {
    int qrow = q0 + l16;
    if (qrow < SS){
      const unsigned short* p = qg + ((size_t)bh*SS + qrow)*64;
      aq[0] = *(const bf16x8*)(p + quad*8);
      aq[1] = *(const bf16x8*)(p + 32 + quad*8);
    } else {
      bf16x8 z8 = {0,0,0,0,0,0,0,0};
      aq[0] = z8; aq[1] = z8;
    }
  }
  f32x4 o[4];
  #pragma unroll
  for (int i=0;i<4;i++) o[i] = (f32x4){0.f,0.f,0.f,0.f};
  float rsum[4] = {0.f,0.f,0.f,0.f};

  const int srow = t >> 2, sc = t & 3;
  const unsigned short* kbase = kg + ((size_t)bh*SS)*64;
  const unsigned short* vbase = vt + ((size_t)bh*64)*SPAD;
  u32x4 rk0, rk1, rv0, rv1;
  rk0 = *(const u32x4*)(kbase + (size_t)srow*64 + sc*8);
  rk1 = *(const u32x4*)(kbase + (size_t)srow*64 + (sc+4)*8);
  rv0 = *(const u32x4*)(vbase + (size_t)srow*SPAD + sc*8);
  rv1 = *(const u32x4*)(vbase + (size_t)srow*SPAD + (sc+4)*8);

  for (int it = 0; it < niter; ++it){
    int k0 = it*64;
    __syncthreads();
    *(u32x4*)(Ks + srow*KSTR + sc*8)     = rk0;
    *(u32x4*)(Ks + srow*KSTR + (sc+4)*8) = rk1;
    *(u32x4*)(Vs + srow*KSTR + sc*8)     = rv0;
    *(u32x4*)(Vs + srow*KSTR + (sc+4)*8) = rv1;
    __syncthreads();
    if (it + 1 < niter){
      int kn = k0 + 64;
      rk0 = *(const u32x4*)(kbase + (size_t)(kn + srow)*64 + sc*8);
      rk1 = *(const u32x4*)(kbase + (size_t)(kn + srow)*64 + (sc+4)*8);
      rv0 = *(const u32x4*)(vbase + (size_t)srow*SPAD + kn + sc*8);
      rv1 = *(const u32x4*)(vbase + (size_t)srow*SPAD + kn + (sc+4)*8);
    }
    float p[2][2][4];
    bool tail = (k0 + 64 > SK);
    #pragma unroll
    for (int h = 0; h < 2; ++h){
      #pragma unroll
      for (int ns = 0; ns < 2; ++ns){
        f32x4 zf = (f32x4){0.f,0.f,0.f,0.f};
        #pragma unroll
        for (int ec = 0; ec < 2; ++ec){
          bf16x8 bkf = *(const bf16x8*)(Ks + (h*32 + 2*l16 + ns)*KSTR + ec*32 + quad*8);
          zf = __builtin_amdgcn_mfma_f32_16x16x32_bf16(aq[ec], bkf, zf, 0,0,0);
        }
        bool valid = !tail || (k0 + h*32 + 2*l16 + ns) < SK;
        #pragma unroll
        for (int rg = 0; rg < 4; ++rg) p[h][ns][rg] = valid ? __expf(zf[rg]) : 0.f;
      }
    }
    unsigned short* Pw = Ps + w*16*KSTR;
    #pragma unroll
    for (int rg = 0; rg < 4; ++rg){
      rsum[rg] += (p[0][0][rg] + p[0][1][rg]) + (p[1][0][rg] + p[1][1][rg]);
      *(unsigned int*)(Pw + (quad*4+rg)*KSTR      + 2*l16) = pk_bf16(p[0][0][rg], p[0][1][rg]);
      *(unsigned int*)(Pw + (quad*4+rg)*KSTR + 32 + 2*l16) = pk_bf16(p[1][0][rg], p[1][1][rg]);
    }
    #pragma unroll
    for (int kc = 0; kc < 2; ++kc){
      bf16x8 ap = *(const bf16x8*)(Pw + l16*KSTR + kc*32 + quad*8);
      #pragma unroll
      for (int nc = 0; nc < 4; ++nc){
        bf16x8 bvf = *(const bf16x8*)(Vs + (nc*16 + l16)*KSTR + kc*32 + quad*8);
        o[nc] = __builtin_amdgcn_mfma_f32_16x16x32_bf16(ap, bvf, o[nc], 0,0,0);
      }
    }
  }
  #pragma unroll
  for (int rg = 0; rg < 4; ++rg){
    float s = rsum[rg];
    #pragma unroll
    for (int off = 8; off >= 1; off >>= 1) s += __shfl_xor(s, off);
    rsum[rg] = s;
  }
  int b = bh / HH, h = bh % HH;
  #pragma unroll
  for (int rg = 0; rg < 4; ++rg){
    int q = q0 + quad*4 + rg;
    if (q >= SS) continue;
    float inv = 1.f / rsum[rg];
    unsigned short* dst = zo + ((size_t)b*SS + q)*384 + h*64;
    #pragma unroll
    for (int nc = 0; nc < 4; ++nc) dst[nc*16 + l16] = f2bf(o[nc][rg]*inv);
  }
}

// ---------------- launch ----------------
extern "C" void kernel_launch(void* const* d_in, const int* in_sizes, int n_in,
                              void* d_out, int out_size, void* d_ws, size_t ws_size,
                              hipStream_t stream){
  const float* x  = (const float*)d_in[0];
  const float* wq = (const float*)d_in[1];
  const float* bq = (const float*)d_in[2];
  const float* wk = (const float*)d_in[3];
  const float* bk = (const float*)d_in[4];
  const float* wv = (const float*)d_in[5];
  const float* bv = (const float*)d_in[6];
  const float* wo = (const float*)d_in[7];
  const float* bo = (const float*)d_in[8];
  const int* kpat = (const int*)d_in[10];
  float* out = (float*)d_out;
  float* out_agg = out + (size_t)MROWS*DD;

  char* ws = (char*)d_ws;
  unsigned short* xb  = (unsigned short*)(ws);
  unsigned short* wbT = (unsigned short*)(ws +  8441856);
  unsigned short* woT = (unsigned short*)(ws +  9326592);
  unsigned short* qg  = (unsigned short*)(ws +  9621504);
  unsigned short* kg  = (unsigned short*)(ws + 18063360);
  unsigned short* vt  = (unsigned short*)(ws + 26505216);
  unsigned short* zo  = (unsigned short*)(ws + 34959360);
  float* xbar         = (float*)(ws + 43401216);
  float* qbar         = (float*)(ws + 43413504);
  (void)in_sizes; (void)n_in; (void)out_size; (void)ws_size;

  hipMemsetAsync(xbar, 0, BB*DD*sizeof(float), stream);
  k_conv_x<<<(MROWS*DD/4 + 255)/256, 256, 0, stream>>>(x, xb, MROWS*DD/4);
  k_conv_w<<<((1152*384 + 384*384) + 255)/256, 256, 0, stream>>>(wq, wk, wv, wo, wbT, woT);
  k_xbar<<<BB*11, DD, 0, stream>>>(x, xbar);
  k_qbar<<<BB, DD, 0, stream>>>(xbar, wq, bq, qbar);
  k_gemm<0><<<86*18, 256, 0, stream>>>(xb, wbT, bq, bk, bv, qg, kg, vt, nullptr);
  k_attn<<<BB*HH*22, 256, 0, stream>>>(qg, kg, vt, zo, kpat);
  k_agg<<<BB*6, 256, 0, stream>>>(qbar, kg, out_agg);
  k_gemm<1><<<86*6, 256, 0, stream>>>(zo, woT, bo, nullptr, nullptr, nullptr, nullptr, nullptr, out);
}

// Round 6
// 208.754 us; speedup vs baseline: 1.1434x; 1.0171x over previous
//
#include <hip/hip_runtime.h>
#include <stdint.h>

#define BB 8
#define SS 1374
#define DD 384
#define HH 6
#define HDIM 64
#define MROWS (BB*SS)   // 10992
#define NPFX 5
#define SPAD 1376       // padded S for vt rows

typedef __attribute__((ext_vector_type(8))) short bf16x8;
typedef __attribute__((ext_vector_type(4))) float f32x4;
typedef __attribute__((ext_vector_type(2))) unsigned int u32x2;
typedef __attribute__((ext_vector_type(4))) unsigned int u32x4;
typedef u32x4 __attribute__((aligned(4))) u32x4_u;

__device__ __forceinline__ unsigned short f2bf(float f){
  union { float f; unsigned int u; } v; v.f = f;
  return (unsigned short)((v.u + 0x7FFFu + ((v.u >> 16) & 1u)) >> 16);
}
__device__ __forceinline__ float bf2f(unsigned short b){
  union { float f; unsigned int u; } v; v.u = ((unsigned int)b) << 16; return v.f;
}
__device__ __forceinline__ unsigned int pk_bf16(float a, float b){
#if __has_builtin(__builtin_amdgcn_cvt_pk_bf16_f32)
  typedef __attribute__((ext_vector_type(2))) __bf16 bfv2;
  bfv2 p = __builtin_amdgcn_cvt_pk_bf16_f32(a, b);
  union { bfv2 v; unsigned int u; } c; c.v = p; return c.u;
#else
  return (unsigned int)f2bf(a) | ((unsigned int)f2bf(b) << 16);
#endif
}

// ---------------- prep kernels ----------------
// fused: bf16 cast of x AND weighted row-sum xbar (reads x once)
__global__ void k_prep_x(const float* __restrict__ x, unsigned short* __restrict__ xb,
                         float* __restrict__ xbar){
  int b = blockIdx.x / 43, ch = blockIdx.x % 43;
  int d = threadIdx.x;
  int s0 = ch*32, s1 = s0 + 32; if (s1 > SS) s1 = SS;
  float acc = 0.f;
  for (int s = s0; s < s1; ++s){
    float v = x[((size_t)b*SS + s)*DD + d];
    float w = (s == 0) ? (1.f/3.f) : (s < 5) ? (1.f/12.f) : (1.f/4107.f);
    acc += w * v;
    xb[((size_t)b*SS + s)*DD + d] = f2bf(v);
  }
  atomicAdd(&xbar[b*DD + d], acc);
}

__global__ void k_conv_w(const float* __restrict__ wq, const float* __restrict__ wk,
                         const float* __restrict__ wv, const float* __restrict__ wo,
                         unsigned short* __restrict__ wbT, unsigned short* __restrict__ woT){
  int i = blockIdx.x*blockDim.x + threadIdx.x;
  if (i < 1152*384){
    int n = i / 384, d = i % 384;
    const float* w = (n < 384) ? wq : (n < 768) ? wk : wv;
    wbT[i] = f2bf(w[(size_t)d*384 + (n % 384)]);
  } else if (i < 1152*384 + 384*384){
    int j = i - 1152*384;
    int n = j / 384, k = j % 384;
    woT[j] = f2bf(wo[(size_t)k*384 + n]);
  }
}

__global__ void k_qbar(const float* __restrict__ xbar, const float* __restrict__ wq,
                       const float* __restrict__ bq, float* __restrict__ qbar){
  __shared__ float xs[DD];
  int b = blockIdx.x, t = threadIdx.x;
  xs[t] = xbar[b*DD + t];
  __syncthreads();
  float acc = bq[t];
  for (int d = 0; d < DD; ++d) acc += xs[d]*wq[(size_t)d*384 + t];
  qbar[b*384 + t] = acc;
}

__global__ void k_agg(const float* __restrict__ qbar, const unsigned short* __restrict__ kg,
                      float* __restrict__ out_agg){
  __shared__ float qs[384];
  int b = blockIdx.x / 6, sb = blockIdx.x % 6;
  int t = threadIdx.x;
  for (int i = t; i < 384; i += 256) qs[i] = qbar[b*384 + i];
  __syncthreads();
  int s = sb*256 + t;
  if (s >= SS) return;
  float acc = 0.f;
  for (int h = 0; h < HH; ++h){
    const unsigned short* kr = kg + (((size_t)(b*HH + h))*SS + s)*64;
    const float* qh = qs + h*64;
    for (int c = 0; c < 8; ++c){
      u32x4 v = *(const u32x4*)(kr + c*8);
      #pragma unroll
      for (int j = 0; j < 4; ++j){
        unsigned int u = v[j];
        acc += qh[c*8 + 2*j]     * bf2f((unsigned short)(u & 0xFFFFu));
        acc += qh[c*8 + 2*j + 1] * bf2f((unsigned short)(u >> 16));
      }
    }
  }
  out_agg[b*SS + s] = acc * (1.f/48.f);
}

// ---------------- MFMA GEMM: 128x64 tile, BK=64 (6 iters), reg prefetch, coalesced epilogue ----
// MODE 0: C(10992x1152) = xb * wbT^T -> qg(*1/8)/kg (B,H,S,64), vt (B,H,64,SPAD), +bias, bf16
// MODE 1: C(10992x384)  = zo * woT^T -> out fp32 + bo
template<int MODE>
__global__ __launch_bounds__(256) void k_gemm(
    const unsigned short* __restrict__ A, const unsigned short* __restrict__ Bt,
    const float* __restrict__ b0, const float* __restrict__ b1, const float* __restrict__ b2,
    unsigned short* __restrict__ qg, unsigned short* __restrict__ kgp,
    unsigned short* __restrict__ vt, float* __restrict__ out)
{
  int mt = blockIdx.x % 86, nt = blockIdx.x / 86;
  const int t = threadIdx.x;
  const int w = t >> 6, lane = t & 63, quad = lane >> 4, l16 = lane & 15;
  const int wm = w >> 1, wn = w & 1;
  constexpr int SMEM_SH = (MODE==0) ? 13824 : 17408;
  __shared__ unsigned short smem[SMEM_SH];
  unsigned short* As = smem;              // [128][72]
  unsigned short* Bs = smem + 9216;       // [64][72]
  f32x4 acc[4][2];
  #pragma unroll
  for (int i=0;i<4;i++){ acc[i][0] = (f32x4){0,0,0,0}; acc[i][1] = (f32x4){0,0,0,0}; }
  const int m0 = mt*128, n0 = nt*64;

  const int ar = t >> 1, akb = (t & 1) * 32;
  int ga = m0 + ar; if (ga > MROWS-1) ga = MROWS-1;
  const unsigned short* ap = A + (size_t)ga*384 + akb;
  const int br = t >> 2, bkb = (t & 3) * 16;
  const unsigned short* bp = Bt + (size_t)(n0 + br)*384 + bkb;

  u32x4 ra[4], rb[2];
  #pragma unroll
  for (int i=0;i<4;i++) ra[i] = *(const u32x4*)(ap + i*8);
  rb[0] = *(const u32x4*)(bp); rb[1] = *(const u32x4*)(bp + 8);

  for (int kc = 0; kc < 6; ++kc){
    __syncthreads();
    #pragma unroll
    for (int i=0;i<4;i++) *(u32x4*)(As + ar*72 + akb + i*8) = ra[i];
    *(u32x4*)(Bs + br*72 + bkb)     = rb[0];
    *(u32x4*)(Bs + br*72 + bkb + 8) = rb[1];
    __syncthreads();
    if (kc + 1 < 6){
      int kn = (kc+1)*64;
      #pragma unroll
      for (int i=0;i<4;i++) ra[i] = *(const u32x4*)(ap + kn + i*8);
      rb[0] = *(const u32x4*)(bp + kn); rb[1] = *(const u32x4*)(bp + kn + 8);
    }
    #pragma unroll
    for (int kh = 0; kh < 2; ++kh){
      bf16x8 af[4], bfr[2];
      #pragma unroll
      for (int rf = 0; rf < 4; ++rf)
        af[rf] = *(const bf16x8*)(As + (wm*64 + rf*16 + l16)*72 + kh*32 + quad*8);
      #pragma unroll
      for (int cf = 0; cf < 2; ++cf)
        bfr[cf] = *(const bf16x8*)(Bs + (wn*32 + cf*16 + l16)*72 + kh*32 + quad*8);
      #pragma unroll
      for (int rf = 0; rf < 4; ++rf)
        #pragma unroll
        for (int cf = 0; cf < 2; ++cf)
          acc[rf][cf] = __builtin_amdgcn_mfma_f32_16x16x32_bf16(af[rf], bfr[cf], acc[rf][cf], 0,0,0);
    }
  }

  const int b0r = m0 / SS, s0r = m0 % SS;
  __syncthreads();
  if (MODE == 1){
    float* CsF = (float*)smem;              // [128][68]
    #pragma unroll
    for (int cf = 0; cf < 2; ++cf){
      int e = wn*32 + cf*16 + l16;
      float bias = b0[n0 + e];
      #pragma unroll
      for (int rf = 0; rf < 4; ++rf){
        int rr = wm*64 + rf*16 + quad*4;
        #pragma unroll
        for (int r4 = 0; r4 < 4; ++r4)
          CsF[(rr + r4)*68 + e] = acc[rf][cf][r4] + bias;
      }
    }
    __syncthreads();
    #pragma unroll
    for (int p = 0; p < 8; ++p){
      int r = p*16 + (t >> 4), c = t & 15;
      int rr = m0 + r;
      if (rr < MROWS){
        f32x4 v = *(const f32x4*)(CsF + r*68 + c*4);
        *(f32x4*)(out + (size_t)rr*384 + n0 + c*4) = v;
      }
    }
  } else {
    const int mat = nt / 6, h = nt - mat*6;
    const float* bvp = (mat==0) ? b0 : (mat==1) ? b1 : b2;
    const float vsc = (mat==0) ? 0.125f : 1.f;
    if (mat < 2){
      unsigned short* Cs = As;
      unsigned short* dst = (mat==0) ? qg : kgp;
      #pragma unroll
      for (int cf = 0; cf < 2; ++cf){
        int e = wn*32 + cf*16 + l16;
        float bias = bvp[h*64 + e];
        #pragma unroll
        for (int rf = 0; rf < 4; ++rf){
          int rr = wm*64 + rf*16 + quad*4;
          #pragma unroll
          for (int r4 = 0; r4 < 4; ++r4)
            Cs[(rr + r4)*72 + e] = f2bf((acc[rf][cf][r4] + bias)*vsc);
        }
      }
      __syncthreads();
      #pragma unroll
      for (int p = 0; p < 4; ++p){
        int r = p*32 + (t >> 3), c = t & 7;
        int rr = m0 + r;
        if (rr < MROWS){
          int s = s0r + r, bb = b0r;
          if (s >= SS){ s -= SS; ++bb; }
          u32x4 v = *(const u32x4*)(Cs + r*72 + c*8);
          *(u32x4*)(dst + (((size_t)(bb*HH + h))*SS + s)*64 + c*8) = v;
        }
      }
    } else {
      unsigned short* CsV = As;               // [64 e][136 s-pad]
      #pragma unroll
      for (int cf = 0; cf < 2; ++cf){
        int e = wn*32 + cf*16 + l16;
        float bias = bvp[h*64 + e];
        #pragma unroll
        for (int rf = 0; rf < 4; ++rf){
          int rr = wm*64 + rf*16 + quad*4;
          #pragma unroll
          for (int p = 0; p < 2; ++p)
            *(unsigned int*)(CsV + e*136 + rr + p*2) =
                pk_bf16(acc[rf][cf][p*2] + bias, acc[rf][cf][p*2+1] + bias);
        }
      }
      __syncthreads();
      const bool nowrap = (s0r + 127 < SS) && (m0 + 127 < MROWS);
      if (nowrap){
        int e = t >> 2;
        unsigned short* vrow = vt + ((size_t)(b0r*HH + h)*64 + e)*SPAD + s0r;
        #pragma unroll
        for (int i = 0; i < 4; ++i){
          int c = (t & 3)*4 + i;
          u32x4 v = *(const u32x4*)(CsV + e*136 + c*8);
          *(u32x4_u*)(vrow + c*8) = v;
        }
      } else {
        for (int idx = t; idx < 64*64; idx += 256){
          int e = idx >> 6, sp = (idx & 63)*2;
          int rr = m0 + sp;
          if (rr < MROWS){
            int s = s0r + sp, bb = b0r;
            if (s >= SS){ s -= SS; ++bb; }
            *(unsigned int*)(vt + ((size_t)(bb*HH + h)*64 + e)*SPAD + s) =
                *(const unsigned int*)(CsV + e*136 + sp);
          }
        }
      }
    }
  }
}

// ---------------- flash attention v4: barrier-free, K/V frags direct from global ----------------
// one wave = 32 queries; LDS only for wave-private P round-trip
__global__ __launch_bounds__(256) void k_attn(
    const unsigned short* __restrict__ qg, const unsigned short* __restrict__ kg,
    const unsigned short* __restrict__ vt, unsigned short* __restrict__ zo,
    const int* __restrict__ kpat)
{
  int t = threadIdx.x, w = t >> 6, lane = t & 63, quad = lane >> 4, l16 = lane & 15;
  int wid = blockIdx.x*4 + w;          // 0..2063 = 48 bh * 43 q-tiles
  int bh = wid / 43, qt = wid - bh*43;
  int q0 = qt*32;
  int SK = NPFX + kpat[0]; if (SK > SS) SK = SS; if (SK < 1) SK = 1;
  int niter = (SK + 63) >> 6;
  __shared__ unsigned short Ps[4][32*72];
  unsigned short* Pw = &Ps[w][0];
  const unsigned short* kbase = kg + ((size_t)bh*SS)*64;
  const unsigned short* vbase = vt + ((size_t)bh*64)*SPAD;

  bf16x8 aq[2][2];
  #pragma unroll
  for (int qf = 0; qf < 2; ++qf){
    int qrow = q0 + qf*16 + l16; if (qrow > SS-1) qrow = SS-1;
    const unsigned short* p = qg + ((size_t)bh*SS + qrow)*64;
    aq[qf][0] = *(const bf16x8*)(p + quad*8);
    aq[qf][1] = *(const bf16x8*)(p + 32 + quad*8);
  }
  f32x4 o[2][4];
  #pragma unroll
  for (int qf=0;qf<2;qf++)
    #pragma unroll
    for (int nc=0;nc<4;nc++) o[qf][nc] = (f32x4){0.f,0.f,0.f,0.f};
  float rsum[2][4] = {{0.f,0.f,0.f,0.f},{0.f,0.f,0.f,0.f}};

  for (int it = 0; it < niter; ++it){
    int k0 = it*64;
    bool tail = (k0 + 64 > SK);
    // QK^T: subtile (ks,ns) covers keys k0 + ks*32 + 2*l16 + ns; K-frag = 16B global load/lane
    #pragma unroll
    for (int ks = 0; ks < 2; ++ks){
      bf16x8 kf[2][2];   // [ns][ec]
      #pragma unroll
      for (int ns = 0; ns < 2; ++ns){
        const unsigned short* kr = kbase + (size_t)(k0 + ks*32 + 2*l16 + ns)*64;
        kf[ns][0] = *(const bf16x8*)(kr + quad*8);
        kf[ns][1] = *(const bf16x8*)(kr + 32 + quad*8);
      }
      #pragma unroll
      for (int qf = 0; qf < 2; ++qf){
        float pp[2][4];
        #pragma unroll
        for (int ns = 0; ns < 2; ++ns){
          f32x4 zf = (f32x4){0.f,0.f,0.f,0.f};
          zf = __builtin_amdgcn_mfma_f32_16x16x32_bf16(aq[qf][0], kf[ns][0], zf, 0,0,0);
          zf = __builtin_amdgcn_mfma_f32_16x16x32_bf16(aq[qf][1], kf[ns][1], zf, 0,0,0);
          bool valid = !tail || (k0 + ks*32 + 2*l16 + ns) < SK;
          #pragma unroll
          for (int rg = 0; rg < 4; ++rg) pp[ns][rg] = valid ? __expf(zf[rg]) : 0.f;
        }
        #pragma unroll
        for (int rg = 0; rg < 4; ++rg){
          rsum[qf][rg] += pp[0][rg] + pp[1][rg];
          *(unsigned int*)(Pw + (qf*16 + quad*4 + rg)*72 + ks*32 + 2*l16) =
              pk_bf16(pp[0][rg], pp[1][rg]);
        }
      }
    }
    // PV: V-frag = 16B global load/lane; P from wave-private LDS (in-order DS pipe, no barrier)
    #pragma unroll
    for (int kc = 0; kc < 2; ++kc){
      bf16x8 ap0 = *(const bf16x8*)(Pw + l16*72        + kc*32 + quad*8);
      bf16x8 ap1 = *(const bf16x8*)(Pw + (16 + l16)*72 + kc*32 + quad*8);
      #pragma unroll
      for (int nc = 0; nc < 4; ++nc){
        bf16x8 vf = *(const bf16x8*)(vbase + (size_t)(nc*16 + l16)*SPAD + k0 + kc*32 + quad*8);
        o[0][nc] = __builtin_amdgcn_mfma_f32_16x16x32_bf16(ap0, vf, o[0][nc], 0,0,0);
        o[1][nc] = __builtin_amdgcn_mfma_f32_16x16x32_bf16(ap1, vf, o[1][nc], 0,0,0);
      }
    }
  }
  // row-sum reduce across the 16 col-lanes, then scale+store
  int b = bh / HH, h = bh - (bh/HH)*HH;
  #pragma unroll
  for (int qf = 0; qf < 2; ++qf){
    #pragma unroll
    for (int rg = 0; rg < 4; ++rg){
      float s = rsum[qf][rg];
      #pragma unroll
      for (int off = 8; off >= 1; off >>= 1) s += __shfl_xor(s, off);
      int q = q0 + qf*16 + quad*4 + rg;
      if (q >= SS) continue;
      float inv = 1.f / s;
      unsigned short* dst = zo + ((size_t)b*SS + q)*384 + h*64;
      #pragma unroll
      for (int nc = 0; nc < 4; ++nc) dst[nc*16 + l16] = f2bf(o[qf][nc][rg]*inv);
    }
  }
}

// ---------------- launch ----------------
extern "C" void kernel_launch(void* const* d_in, const int* in_sizes, int n_in,
                              void* d_out, int out_size, void* d_ws, size_t ws_size,
                              hipStream_t stream){
  const float* x  = (const float*)d_in[0];
  const float* wq = (const float*)d_in[1];
  const float* bq = (const float*)d_in[2];
  const float* wk = (const float*)d_in[3];
  const float* bk = (const float*)d_in[4];
  const float* wv = (const float*)d_in[5];
  const float* bv = (const float*)d_in[6];
  const float* wo = (const float*)d_in[7];
  const float* bo = (const float*)d_in[8];
  const int* kpat = (const int*)d_in[10];
  float* out = (float*)d_out;
  float* out_agg = out + (size_t)MROWS*DD;

  char* ws = (char*)d_ws;
  unsigned short* xb  = (unsigned short*)(ws);
  unsigned short* wbT = (unsigned short*)(ws +  8441856);
  unsigned short* woT = (unsigned short*)(ws +  9326592);
  unsigned short* qg  = (unsigned short*)(ws +  9621504);
  unsigned short* kg  = (unsigned short*)(ws + 18063360);
  unsigned short* vt  = (unsigned short*)(ws + 26505216);
  unsigned short* zo  = (unsigned short*)(ws + 34959360);
  float* xbar         = (float*)(ws + 43401216);
  float* qbar         = (float*)(ws + 43413504);
  (void)in_sizes; (void)n_in; (void)out_size; (void)ws_size;

  hipMemsetAsync(xbar, 0, BB*DD*sizeof(float), stream);
  k_prep_x<<<BB*43, DD, 0, stream>>>(x, xb, xbar);
  k_conv_w<<<((1152*384 + 384*384) + 255)/256, 256, 0, stream>>>(wq, wk, wv, wo, wbT, woT);
  k_qbar<<<BB, DD, 0, stream>>>(xbar, wq, bq, qbar);
  k_gemm<0><<<86*18, 256, 0, stream>>>(xb, wbT, bq, bk, bv, qg, kg, vt, nullptr);
  k_attn<<<516, 256, 0, stream>>>(qg, kg, vt, zo, kpat);
  k_agg<<<BB*6, 256, 0, stream>>>(qbar, kg, out_agg);
  k_gemm<1><<<86*6, 256, 0, stream>>>(zo, woT, bo, nullptr, nullptr, nullptr, nullptr, nullptr, out);
}

// Round 7
// 198.271 us; speedup vs baseline: 1.2038x; 1.0529x over previous
//
#include <hip/hip_runtime.h>
#include <stdint.h>

#define BB 8
#define SS 1374
#define DD 384
#define HH 6
#define HDIM 64
#define MROWS (BB*SS)   // 10992
#define NPFX 5
#define SPAD 1376       // padded S for vt rows

typedef __attribute__((ext_vector_type(8))) short bf16x8;
typedef __attribute__((ext_vector_type(4))) float f32x4;
typedef __attribute__((ext_vector_type(2))) unsigned int u32x2;
typedef __attribute__((ext_vector_type(4))) unsigned int u32x4;
typedef u32x4 __attribute__((aligned(4))) u32x4_u;

__device__ __forceinline__ unsigned short f2bf(float f){
  union { float f; unsigned int u; } v; v.f = f;
  return (unsigned short)((v.u + 0x7FFFu + ((v.u >> 16) & 1u)) >> 16);
}
__device__ __forceinline__ float bf2f(unsigned short b){
  union { float f; unsigned int u; } v; v.u = ((unsigned int)b) << 16; return v.f;
}
__device__ __forceinline__ unsigned int pk_bf16(float a, float b){
#if __has_builtin(__builtin_amdgcn_cvt_pk_bf16_f32)
  typedef __attribute__((ext_vector_type(2))) __bf16 bfv2;
  bfv2 p = __builtin_amdgcn_cvt_pk_bf16_f32(a, b);
  union { bfv2 v; unsigned int u; } c; c.v = p; return c.u;
#else
  return (unsigned int)f2bf(a) | ((unsigned int)f2bf(b) << 16);
#endif
}

// ---------------- prep kernels ----------------
__global__ void k_prep_x(const float* __restrict__ x, unsigned short* __restrict__ xb,
                         float* __restrict__ xbar){
  int b = blockIdx.x / 43, ch = blockIdx.x % 43;
  int d = threadIdx.x;
  int s0 = ch*32, s1 = s0 + 32; if (s1 > SS) s1 = SS;
  float acc = 0.f;
  for (int s = s0; s < s1; ++s){
    float v = x[((size_t)b*SS + s)*DD + d];
    float w = (s == 0) ? (1.f/3.f) : (s < 5) ? (1.f/12.f) : (1.f/4107.f);
    acc += w * v;
    xb[((size_t)b*SS + s)*DD + d] = f2bf(v);
  }
  atomicAdd(&xbar[b*DD + d], acc);
}

__global__ void k_conv_w(const float* __restrict__ wq, const float* __restrict__ wk,
                         const float* __restrict__ wv, const float* __restrict__ wo,
                         unsigned short* __restrict__ wbT, unsigned short* __restrict__ woT){
  int i = blockIdx.x*blockDim.x + threadIdx.x;
  if (i < 1152*384){
    int n = i / 384, d = i % 384;
    const float* w = (n < 384) ? wq : (n < 768) ? wk : wv;
    wbT[i] = f2bf(w[(size_t)d*384 + (n % 384)]);
  } else if (i < 1152*384 + 384*384){
    int j = i - 1152*384;
    int n = j / 384, k = j % 384;
    woT[j] = f2bf(wo[(size_t)k*384 + n]);
  }
}

__global__ void k_qbar(const float* __restrict__ xbar, const float* __restrict__ wq,
                       const float* __restrict__ bq, float* __restrict__ qbar){
  __shared__ float xs[DD];
  int b = blockIdx.x, t = threadIdx.x;
  xs[t] = xbar[b*DD + t];
  __syncthreads();
  float acc = bq[t];
  for (int d = 0; d < DD; ++d) acc += xs[d]*wq[(size_t)d*384 + t];
  qbar[b*384 + t] = acc;
}

__global__ void k_agg(const float* __restrict__ qbar, const unsigned short* __restrict__ kg,
                      float* __restrict__ out_agg){
  __shared__ float qs[384];
  int b = blockIdx.x / 6, sb = blockIdx.x % 6;
  int t = threadIdx.x;
  for (int i = t; i < 384; i += 256) qs[i] = qbar[b*384 + i];
  __syncthreads();
  int s = sb*256 + t;
  if (s >= SS) return;
  float acc = 0.f;
  for (int h = 0; h < HH; ++h){
    const unsigned short* kr = kg + (((size_t)(b*HH + h))*SS + s)*64;
    const float* qh = qs + h*64;
    for (int c = 0; c < 8; ++c){
      u32x4 v = *(const u32x4*)(kr + c*8);
      #pragma unroll
      for (int j = 0; j < 4; ++j){
        unsigned int u = v[j];
        acc += qh[c*8 + 2*j]     * bf2f((unsigned short)(u & 0xFFFFu));
        acc += qh[c*8 + 2*j + 1] * bf2f((unsigned short)(u >> 16));
      }
    }
  }
  out_agg[b*SS + s] = acc * (1.f/48.f);
}

// ---------------- MFMA GEMM: 128x64 tile, BK=64 (6 iters), reg prefetch, coalesced epilogue ----
template<int MODE>
__global__ __launch_bounds__(256) void k_gemm(
    const unsigned short* __restrict__ A, const unsigned short* __restrict__ Bt,
    const float* __restrict__ b0, const float* __restrict__ b1, const float* __restrict__ b2,
    unsigned short* __restrict__ qg, unsigned short* __restrict__ kgp,
    unsigned short* __restrict__ vt, float* __restrict__ out)
{
  int mt = blockIdx.x % 86, nt = blockIdx.x / 86;
  const int t = threadIdx.x;
  const int w = t >> 6, lane = t & 63, quad = lane >> 4, l16 = lane & 15;
  const int wm = w >> 1, wn = w & 1;
  constexpr int SMEM_SH = (MODE==0) ? 13824 : 17408;
  __shared__ unsigned short smem[SMEM_SH];
  unsigned short* As = smem;              // [128][72]
  unsigned short* Bs = smem + 9216;       // [64][72]
  f32x4 acc[4][2];
  #pragma unroll
  for (int i=0;i<4;i++){ acc[i][0] = (f32x4){0,0,0,0}; acc[i][1] = (f32x4){0,0,0,0}; }
  const int m0 = mt*128, n0 = nt*64;

  const int ar = t >> 1, akb = (t & 1) * 32;
  int ga = m0 + ar; if (ga > MROWS-1) ga = MROWS-1;
  const unsigned short* ap = A + (size_t)ga*384 + akb;
  const int br = t >> 2, bkb = (t & 3) * 16;
  const unsigned short* bp = Bt + (size_t)(n0 + br)*384 + bkb;

  u32x4 ra[4], rb[2];
  #pragma unroll
  for (int i=0;i<4;i++) ra[i] = *(const u32x4*)(ap + i*8);
  rb[0] = *(const u32x4*)(bp); rb[1] = *(const u32x4*)(bp + 8);

  for (int kc = 0; kc < 6; ++kc){
    __syncthreads();
    #pragma unroll
    for (int i=0;i<4;i++) *(u32x4*)(As + ar*72 + akb + i*8) = ra[i];
    *(u32x4*)(Bs + br*72 + bkb)     = rb[0];
    *(u32x4*)(Bs + br*72 + bkb + 8) = rb[1];
    __syncthreads();
    if (kc + 1 < 6){
      int kn = (kc+1)*64;
      #pragma unroll
      for (int i=0;i<4;i++) ra[i] = *(const u32x4*)(ap + kn + i*8);
      rb[0] = *(const u32x4*)(bp + kn); rb[1] = *(const u32x4*)(bp + kn + 8);
    }
    #pragma unroll
    for (int kh = 0; kh < 2; ++kh){
      bf16x8 af[4], bfr[2];
      #pragma unroll
      for (int rf = 0; rf < 4; ++rf)
        af[rf] = *(const bf16x8*)(As + (wm*64 + rf*16 + l16)*72 + kh*32 + quad*8);
      #pragma unroll
      for (int cf = 0; cf < 2; ++cf)
        bfr[cf] = *(const bf16x8*)(Bs + (wn*32 + cf*16 + l16)*72 + kh*32 + quad*8);
      #pragma unroll
      for (int rf = 0; rf < 4; ++rf)
        #pragma unroll
        for (int cf = 0; cf < 2; ++cf)
          acc[rf][cf] = __builtin_amdgcn_mfma_f32_16x16x32_bf16(af[rf], bfr[cf], acc[rf][cf], 0,0,0);
    }
  }

  const int b0r = m0 / SS, s0r = m0 % SS;
  __syncthreads();
  if (MODE == 1){
    float* CsF = (float*)smem;              // [128][68]
    #pragma unroll
    for (int cf = 0; cf < 2; ++cf){
      int e = wn*32 + cf*16 + l16;
      float bias = b0[n0 + e];
      #pragma unroll
      for (int rf = 0; rf < 4; ++rf){
        int rr = wm*64 + rf*16 + quad*4;
        #pragma unroll
        for (int r4 = 0; r4 < 4; ++r4)
          CsF[(rr + r4)*68 + e] = acc[rf][cf][r4] + bias;
      }
    }
    __syncthreads();
    #pragma unroll
    for (int p = 0; p < 8; ++p){
      int r = p*16 + (t >> 4), c = t & 15;
      int rr = m0 + r;
      if (rr < MROWS){
        f32x4 v = *(const f32x4*)(CsF + r*68 + c*4);
        *(f32x4*)(out + (size_t)rr*384 + n0 + c*4) = v;
      }
    }
  } else {
    const int mat = nt / 6, h = nt - mat*6;
    const float* bvp = (mat==0) ? b0 : (mat==1) ? b1 : b2;
    const float vsc = (mat==0) ? 0.125f : 1.f;
    if (mat < 2){
      unsigned short* Cs = As;
      unsigned short* dst = (mat==0) ? qg : kgp;
      #pragma unroll
      for (int cf = 0; cf < 2; ++cf){
        int e = wn*32 + cf*16 + l16;
        float bias = bvp[h*64 + e];
        #pragma unroll
        for (int rf = 0; rf < 4; ++rf){
          int rr = wm*64 + rf*16 + quad*4;
          #pragma unroll
          for (int r4 = 0; r4 < 4; ++r4)
            Cs[(rr + r4)*72 + e] = f2bf((acc[rf][cf][r4] + bias)*vsc);
        }
      }
      __syncthreads();
      #pragma unroll
      for (int p = 0; p < 4; ++p){
        int r = p*32 + (t >> 3), c = t & 7;
        int rr = m0 + r;
        if (rr < MROWS){
          int s = s0r + r, bb = b0r;
          if (s >= SS){ s -= SS; ++bb; }
          u32x4 v = *(const u32x4*)(Cs + r*72 + c*8);
          *(u32x4*)(dst + (((size_t)(bb*HH + h))*SS + s)*64 + c*8) = v;
        }
      }
    } else {
      unsigned short* CsV = As;               // [64 e][136 s-pad]
      #pragma unroll
      for (int cf = 0; cf < 2; ++cf){
        int e = wn*32 + cf*16 + l16;
        float bias = bvp[h*64 + e];
        #pragma unroll
        for (int rf = 0; rf < 4; ++rf){
          int rr = wm*64 + rf*16 + quad*4;
          #pragma unroll
          for (int p = 0; p < 2; ++p)
            *(unsigned int*)(CsV + e*136 + rr + p*2) =
                pk_bf16(acc[rf][cf][p*2] + bias, acc[rf][cf][p*2+1] + bias);
        }
      }
      __syncthreads();
      const bool nowrap = (s0r + 127 < SS) && (m0 + 127 < MROWS);
      if (nowrap){
        int e = t >> 2;
        unsigned short* vrow = vt + ((size_t)(b0r*HH + h)*64 + e)*SPAD + s0r;
        #pragma unroll
        for (int i = 0; i < 4; ++i){
          int c = (t & 3)*4 + i;
          u32x4 v = *(const u32x4*)(CsV + e*136 + c*8);
          *(u32x4_u*)(vrow + c*8) = v;
        }
      } else {
        for (int idx = t; idx < 64*64; idx += 256){
          int e = idx >> 6, sp = (idx & 63)*2;
          int rr = m0 + sp;
          if (rr < MROWS){
            int s = s0r + sp, bb = b0r;
            if (s >= SS){ s -= SS; ++bb; }
            *(unsigned int*)(vt + ((size_t)(bb*HH + h)*64 + e)*SPAD + s) =
                *(const unsigned int*)(CsV + e*136 + sp);
          }
        }
      }
    }
  }
}

// ---------------- flash attention v5: barrier-free + register double-buffered K, early V ----
// 2 waves/block, 32 queries/wave; LDS only for wave-private P round-trip
__global__ __launch_bounds__(128) void k_attn(
    const unsigned short* __restrict__ qg, const unsigned short* __restrict__ kg,
    const unsigned short* __restrict__ vt, unsigned short* __restrict__ zo,
    const int* __restrict__ kpat)
{
  int t = threadIdx.x, w = t >> 6, lane = t & 63, quad = lane >> 4, l16 = lane & 15;
  int wid = blockIdx.x*2 + w;          // 0..2063 = 48 bh * 43 q-tiles
  int bh = wid / 43, qt = wid - bh*43;
  int q0 = qt*32;
  int SK = NPFX + kpat[0]; if (SK > SS) SK = SS; if (SK < 1) SK = 1;
  int niter = (SK + 63) >> 6;
  __shared__ unsigned short Ps[2][32*72];
  unsigned short* Pw = &Ps[w][0];
  const unsigned short* kbase = kg + ((size_t)bh*SS)*64;
  const unsigned short* vbase = vt + ((size_t)bh*64)*SPAD;

  bf16x8 aq[2][2];
  #pragma unroll
  for (int qf = 0; qf < 2; ++qf){
    int qrow = q0 + qf*16 + l16; if (qrow > SS-1) qrow = SS-1;
    const unsigned short* p = qg + ((size_t)bh*SS + qrow)*64;
    aq[qf][0] = *(const bf16x8*)(p + quad*8);
    aq[qf][1] = *(const bf16x8*)(p + 32 + quad*8);
  }
  f32x4 o[2][4];
  #pragma unroll
  for (int qf=0;qf<2;qf++)
    #pragma unroll
    for (int nc=0;nc<4;nc++) o[qf][nc] = (f32x4){0.f,0.f,0.f,0.f};
  float rsum[2][4] = {{0.f,0.f,0.f,0.f},{0.f,0.f,0.f,0.f}};

  auto loadK = [&](int k0, bf16x8 (&kf)[2][2][2]){
    #pragma unroll
    for (int ks = 0; ks < 2; ++ks)
      #pragma unroll
      for (int ns = 0; ns < 2; ++ns){
        const unsigned short* kr = kbase + (size_t)(k0 + ks*32 + 2*l16 + ns)*64;
        kf[ks][ns][0] = *(const bf16x8*)(kr + quad*8);
        kf[ks][ns][1] = *(const bf16x8*)(kr + 32 + quad*8);
      }
  };

  auto body = [&](int it, bf16x8 (&kfC)[2][2][2], bf16x8 (&kfN)[2][2][2]){
    int k0 = it*64;
    // current-iter V frags issued EARLY (consumed only in PV at the end)
    bf16x8 vf[2][4];
    #pragma unroll
    for (int kc = 0; kc < 2; ++kc)
      #pragma unroll
      for (int nc = 0; nc < 4; ++nc)
        vf[kc][nc] = *(const bf16x8*)(vbase + (size_t)(nc*16 + l16)*SPAD + k0 + kc*32 + quad*8);
    // next-iter K frags (ping-pong register buffer)
    if (it + 1 < niter) loadK(k0 + 64, kfN);
    bool tail = (k0 + 64 > SK);
    // QK^T + exp + P->LDS
    #pragma unroll
    for (int ks = 0; ks < 2; ++ks){
      #pragma unroll
      for (int qf = 0; qf < 2; ++qf){
        float pp[2][4];
        #pragma unroll
        for (int ns = 0; ns < 2; ++ns){
          f32x4 zf = (f32x4){0.f,0.f,0.f,0.f};
          zf = __builtin_amdgcn_mfma_f32_16x16x32_bf16(aq[qf][0], kfC[ks][ns][0], zf, 0,0,0);
          zf = __builtin_amdgcn_mfma_f32_16x16x32_bf16(aq[qf][1], kfC[ks][ns][1], zf, 0,0,0);
          bool valid = !tail || (k0 + ks*32 + 2*l16 + ns) < SK;
          #pragma unroll
          for (int rg = 0; rg < 4; ++rg) pp[ns][rg] = valid ? __expf(zf[rg]) : 0.f;
        }
        #pragma unroll
        for (int rg = 0; rg < 4; ++rg){
          rsum[qf][rg] += pp[0][rg] + pp[1][rg];
          *(unsigned int*)(Pw + (qf*16 + quad*4 + rg)*72 + ks*32 + 2*l16) =
              pk_bf16(pp[0][rg], pp[1][rg]);
        }
      }
    }
    // PV (P via wave-private LDS round-trip; no barrier needed)
    #pragma unroll
    for (int kc = 0; kc < 2; ++kc){
      bf16x8 ap0 = *(const bf16x8*)(Pw + l16*72        + kc*32 + quad*8);
      bf16x8 ap1 = *(const bf16x8*)(Pw + (16 + l16)*72 + kc*32 + quad*8);
      #pragma unroll
      for (int nc = 0; nc < 4; ++nc){
        o[0][nc] = __builtin_amdgcn_mfma_f32_16x16x32_bf16(ap0, vf[kc][nc], o[0][nc], 0,0,0);
        o[1][nc] = __builtin_amdgcn_mfma_f32_16x16x32_bf16(ap1, vf[kc][nc], o[1][nc], 0,0,0);
      }
    }
  };

  bf16x8 kfA[2][2][2], kfB[2][2][2];
  loadK(0, kfA);
  for (int it = 0; it < niter; it += 2){
    body(it, kfA, kfB);
    if (it + 1 < niter) body(it + 1, kfB, kfA);
  }

  int b = bh / HH, h = bh - (bh/HH)*HH;
  #pragma unroll
  for (int qf = 0; qf < 2; ++qf){
    #pragma unroll
    for (int rg = 0; rg < 4; ++rg){
      float s = rsum[qf][rg];
      #pragma unroll
      for (int off = 8; off >= 1; off >>= 1) s += __shfl_xor(s, off);
      int q = q0 + qf*16 + quad*4 + rg;
      if (q >= SS) continue;
      float inv = 1.f / s;
      unsigned short* dst = zo + ((size_t)b*SS + q)*384 + h*64;
      #pragma unroll
      for (int nc = 0; nc < 4; ++nc) dst[nc*16 + l16] = f2bf(o[qf][nc][rg]*inv);
    }
  }
}

// ---------------- launch ----------------
extern "C" void kernel_launch(void* const* d_in, const int* in_sizes, int n_in,
                              void* d_out, int out_size, void* d_ws, size_t ws_size,
                              hipStream_t stream){
  const float* x  = (const float*)d_in[0];
  const float* wq = (const float*)d_in[1];
  const float* bq = (const float*)d_in[2];
  const float* wk = (const float*)d_in[3];
  const float* bk = (const float*)d_in[4];
  const float* wv = (const float*)d_in[5];
  const float* bv = (const float*)d_in[6];
  const float* wo = (const float*)d_in[7];
  const float* bo = (const float*)d_in[8];
  const int* kpat = (const int*)d_in[10];
  float* out = (float*)d_out;
  float* out_agg = out + (size_t)MROWS*DD;

  char* ws = (char*)d_ws;
  unsigned short* xb  = (unsigned short*)(ws);
  unsigned short* wbT = (unsigned short*)(ws +  8441856);
  unsigned short* woT = (unsigned short*)(ws +  9326592);
  unsigned short* qg  = (unsigned short*)(ws +  9621504);
  unsigned short* kg  = (unsigned short*)(ws + 18063360);
  unsigned short* vt  = (unsigned short*)(ws + 26505216);
  unsigned short* zo  = (unsigned short*)(ws + 34959360);
  float* xbar         = (float*)(ws + 43401216);
  float* qbar         = (float*)(ws + 43413504);
  (void)in_sizes; (void)n_in; (void)out_size; (void)ws_size;

  hipMemsetAsync(xbar, 0, BB*DD*sizeof(float), stream);
  k_prep_x<<<BB*43, DD, 0, stream>>>(x, xb, xbar);
  k_conv_w<<<((1152*384 + 384*384) + 255)/256, 256, 0, stream>>>(wq, wk, wv, wo, wbT, woT);
  k_qbar<<<BB, DD, 0, stream>>>(xbar, wq, bq, qbar);
  k_gemm<0><<<86*18, 256, 0, stream>>>(xb, wbT, bq, bk, bv, qg, kg, vt, nullptr);
  k_attn<<<1032, 128, 0, stream>>>(qg, kg, vt, zo, kpat);
  k_agg<<<BB*6, 256, 0, stream>>>(qbar, kg, out_agg);
  k_gemm<1><<<86*6, 256, 0, stream>>>(zo, woT, bo, nullptr, nullptr, nullptr, nullptr, nullptr, out);
}